// Round 14
// baseline (1103.663 us; speedup 1.0000x reference)
//
#include <hip/hip_runtime.h>
#include <stdint.h>

// ---- problem constants (fixed by the reference) ----
#define B_ 4
#define T_ 1024
#define C_ 768
#define H_ 12
#define D_ 64
#define F_ 3072
#define V_ 32000
#define L_ 4

typedef unsigned short ushort_t;
typedef __bf16 bf16x8 __attribute__((ext_vector_type(8)));
typedef float f32x4 __attribute__((ext_vector_type(4)));
typedef unsigned short u16x8 __attribute__((ext_vector_type(8)));

__device__ __forceinline__ float b2f(unsigned short u) {
    union { unsigned int i; float f; } x; x.i = ((unsigned int)u) << 16; return x.f;
}
__device__ __forceinline__ unsigned short f2b(float f) {
    union { float f; unsigned int i; } x; x.f = f;
    unsigned int r = x.i + 0x7FFFu + ((x.i >> 16) & 1u);
    return (unsigned short)(r >> 16);
}

// fast exact-GELU: erf via Abramowitz-Stegun 7.1.26 (|eps| <= 1.5e-7)
__device__ __forceinline__ float gelu_f(float u) {
    float z = fabsf(u) * 0.70710678118654752f;
    float t = __builtin_amdgcn_rcpf(1.0f + 0.3275911f * z);
    float poly = t * (0.254829592f + t * (-0.284496736f + t * (1.421413741f +
                 t * (-1.453152027f + t * 1.061405429f))));
    float erfz = 1.0f - poly * __expf(-z * z);
    return u * 0.5f * (1.0f + copysignf(erfz, u));
}

// async global->LDS, 16B per lane; LDS dest = wave-uniform base, HW scatters lane*16B
__device__ __forceinline__ void gload16(const ushort_t* g, ushort_t* l) {
    __builtin_amdgcn_global_load_lds(
        (const __attribute__((address_space(1))) unsigned int*)g,
        (__attribute__((address_space(3))) unsigned int*)l, 16, 0, 0);
}

// ---------------------------------------------------------------------------
// embedding
// ---------------------------------------------------------------------------
__global__ __launch_bounds__(256) void k_embed(const int* __restrict__ idx,
        const float* __restrict__ tok, const float* __restrict__ pos,
        float* __restrict__ x) {
    int i = blockIdx.x * 256 + threadIdx.x;
    int m = i / (C_ / 4);
    int cc = (i % (C_ / 4)) * 4;
    int t = m & (T_ - 1);
    int tokid = idx[m];
    float4 te = *(const float4*)&tok[(size_t)tokid * C_ + cc];
    float4 pe = *(const float4*)&pos[(size_t)t * C_ + cc];
    *(float4*)&x[(size_t)m * C_ + cc] =
        make_float4(te.x + pe.x, te.y + pe.y, te.z + pe.z, te.w + pe.w);
}

// ---------------------------------------------------------------------------
// LayerNorm: one ROW per WAVE, 4 rows/block.
// ---------------------------------------------------------------------------
__global__ __launch_bounds__(256) void k_ln(const float* __restrict__ x,
        const float* __restrict__ s, const float* __restrict__ b,
        ushort_t* __restrict__ out) {
    const int lane = threadIdx.x & 63, wave = threadIdx.x >> 6;
    const int row = blockIdx.x * 4 + wave;
    const float* xr = x + (size_t)row * C_;
    float4 v[3];
    float sum = 0.f, sq = 0.f;
#pragma unroll
    for (int j = 0; j < 3; ++j) {
        v[j] = *(const float4*)&xr[lane * 4 + j * 256];
        sum += v[j].x + v[j].y + v[j].z + v[j].w;
        sq  += v[j].x * v[j].x + v[j].y * v[j].y + v[j].z * v[j].z + v[j].w * v[j].w;
    }
#pragma unroll
    for (int off = 1; off < 64; off <<= 1) {
        sum += __shfl_xor(sum, off);
        sq  += __shfl_xor(sq,  off);
    }
    float mean = sum * (1.f / C_);
    float var  = sq * (1.f / C_) - mean * mean;
    float rstd = rsqrtf(var + 1e-5f);
#pragma unroll
    for (int j = 0; j < 3; ++j) {
        int c = lane * 4 + j * 256;
        float4 sv = *(const float4*)&s[c];
        float4 bv = *(const float4*)&b[c];
        ushort4 o;
        o.x = f2b((v[j].x - mean) * rstd * sv.x + bv.x);
        o.y = f2b((v[j].y - mean) * rstd * sv.y + bv.y);
        o.z = f2b((v[j].z - mean) * rstd * sv.z + bv.z);
        o.w = f2b((v[j].w - mean) * rstd * sv.w + bv.w);
        *(ushort4*)&out[(size_t)row * C_ + c] = o;
    }
}

// ---------------------------------------------------------------------------
// batched weight transpose+convert: f32 [R,C] -> bf16 [C,R]
// ---------------------------------------------------------------------------
__global__ void k_tcvt(const float* __restrict__ in, ushort_t* __restrict__ out,
                       int R, int C) {
    __shared__ float tile[32][33];
    const float* src = in + (size_t)blockIdx.z * R * C;
    ushort_t* dst = out + (size_t)blockIdx.z * R * C;
    int r0 = blockIdx.y * 32, c0 = blockIdx.x * 32;
    int tx = threadIdx.x, ty = threadIdx.y;
#pragma unroll
    for (int i = ty; i < 32; i += 8)
        tile[i][tx] = src[(size_t)(r0 + i) * C + c0 + tx];
    __syncthreads();
#pragma unroll
    for (int i = ty; i < 32; i += 8)
        dst[(size_t)(c0 + i) * R + r0 + tx] = f2b(tile[tx][i]);
}

__global__ void k_tcvt16(const float* __restrict__ wq, const float* __restrict__ wk,
                         const float* __restrict__ wv, const float* __restrict__ wp,
                         ushort_t* __restrict__ out) {
    __shared__ float tile[32][33];
    int l = blockIdx.z >> 2, w = blockIdx.z & 3;
    const float* src = (w == 0 ? wq : w == 1 ? wk : w == 2 ? wv : wp) + (size_t)l * C_ * C_;
    ushort_t* dst = out + (size_t)blockIdx.z * C_ * C_;
    int r0 = blockIdx.y * 32, c0 = blockIdx.x * 32;
    int tx = threadIdx.x, ty = threadIdx.y;
#pragma unroll
    for (int i = ty; i < 32; i += 8)
        tile[i][tx] = src[(size_t)(r0 + i) * C_ + c0 + tx];
    __syncthreads();
#pragma unroll
    for (int i = ty; i < 32; i += 8)
        dst[(size_t)(c0 + i) * C_ + r0 + tx] = f2b(tile[tx][i]);
}

// ---------------------------------------------------------------------------
// GEMM 128x128: BK=32, 4 waves, 3-buffer ring, counted vmcnt(4),
// slot-XOR swizzle, supertile order, one barrier per K-step.
// EPI: 0 = f32 NT wide store (head)  1 = +bias GELU wide bf16
//      2 = +bias +resid f32 wide     3 = QKV scatter
// ---------------------------------------------------------------------------
template <int EPI>
__global__ __launch_bounds__(256) void k_gemm(
        const ushort_t* __restrict__ A, const ushort_t* __restrict__ BT,
        const float* __restrict__ bias, const float* __restrict__ resid,
        float* __restrict__ outf, ushort_t* __restrict__ outb,
        ushort_t* __restrict__ outb2, ushort_t* __restrict__ outb3,
        int M, int N, int K) {
    __shared__ __align__(16) ushort_t S[24576];
    const int tid = threadIdx.x;
    const int lane = tid & 63, wave = tid >> 6;
    const int lr = lane & 15, lg = lane >> 4;
    const int wm = (wave >> 1) * 64, wn = (wave & 1) * 64;

    const int bid = blockIdx.x;
    const int m_in = bid & 7;
    const int strip = (bid >> 3) & 3;
    const int ncol = bid >> 5;
    const int m0 = (strip * 8 + m_in) << 7;
    const int n0 = ncol << 7;

    const int sr = wave * 16 + (lane >> 2);
    const int sc = (((lane & 3) ^ ((lane >> 3) & 3)) << 3);

    f32x4 acc[4][4];
#pragma unroll
    for (int i = 0; i < 4; ++i)
#pragma unroll
        for (int j = 0; j < 4; ++j) acc[i][j] = (f32x4){0.f, 0.f, 0.f, 0.f};

    auto stage = [&](int k0, int buf) {
        ushort_t* as = S + buf * 4096;
        ushort_t* bs = S + 12288 + buf * 4096;
        gload16(&A [(size_t)(m0 + sr)      * K + k0 + sc], as + (wave * 16) * 32);
        gload16(&A [(size_t)(m0 + 64 + sr) * K + k0 + sc], as + (64 + wave * 16) * 32);
        gload16(&BT[(size_t)(n0 + sr)      * K + k0 + sc], bs + (wave * 16) * 32);
        gload16(&BT[(size_t)(n0 + 64 + sr) * K + k0 + sc], bs + (64 + wave * 16) * 32);
    };

    const int nt = K >> 5;
    stage(0, 0);
    stage(32, 1);
    int cur = 0, pre = 2;
    const int swzr = (lr >> 1) & 3;
    for (int t = 0; t < nt; ++t) {
        if (t + 1 < nt) asm volatile("s_waitcnt vmcnt(4)" ::: "memory");
        else            asm volatile("s_waitcnt vmcnt(0)" ::: "memory");
        __builtin_amdgcn_sched_barrier(0);
        __builtin_amdgcn_s_barrier();
        const ushort_t* as = S + cur * 4096;
        const ushort_t* bs = S + 12288 + cur * 4096;
        bf16x8 af[4], bfr[4];
#pragma unroll
        for (int i = 0; i < 4; ++i)
            af[i]  = *(const bf16x8*)&as[(wm + i * 16 + lr) * 32 + ((lg ^ swzr) << 3)];
#pragma unroll
        for (int j = 0; j < 4; ++j)
            bfr[j] = *(const bf16x8*)&bs[(wn + j * 16 + lr) * 32 + ((lg ^ swzr) << 3)];
        if (t + 2 < nt) stage((t + 2) << 5, pre);
#pragma unroll
        for (int i = 0; i < 4; ++i)
#pragma unroll
            for (int j = 0; j < 4; ++j)
                acc[i][j] = __builtin_amdgcn_mfma_f32_16x16x32_bf16(af[i], bfr[j], acc[i][j], 0, 0, 0);
        cur = (cur == 2) ? 0 : cur + 1;
        pre = (pre == 2) ? 0 : pre + 1;
    }

    if (EPI == 0 || EPI == 2) {
        float* cls = (float*)S;                       // [64][128] f32 = 32KB
#pragma unroll
        for (int h = 0; h < 2; ++h) {
            __syncthreads();
            if ((wm >> 6) == h) {
#pragma unroll
                for (int i = 0; i < 4; ++i)
#pragma unroll
                    for (int j = 0; j < 4; ++j)
#pragma unroll
                        for (int r = 0; r < 4; ++r)
                            cls[(i * 16 + lg * 4 + r) * 128 + wn + j * 16 + lr] = acc[i][j][r];
            }
            __syncthreads();
#pragma unroll
            for (int p = 0; p < 8; ++p) {
                int row = p * 8 + (tid >> 5);
                int colc = (tid & 31) * 4;
                f32x4 val = *(const f32x4*)&cls[row * 128 + colc];
                size_t gidx = (size_t)(m0 + h * 64 + row) * N + n0 + colc;
                if (EPI == 2) {
                    f32x4 rv = *(const f32x4*)&resid[gidx];
                    f32x4 bv = *(const f32x4*)&bias[n0 + colc];
                    val = val + rv + bv;
                    *(f32x4*)&outf[gidx] = val;
                } else {
                    __builtin_nontemporal_store(val, (f32x4*)&outf[gidx]);
                }
            }
        }
        return;
    }

    if (EPI == 1) {
        ushort_t* cls = S;                            // [128][128] bf16 = 32KB
        __syncthreads();
#pragma unroll
        for (int i = 0; i < 4; ++i)
#pragma unroll
            for (int j = 0; j < 4; ++j) {
                float bval = bias[n0 + wn + j * 16 + lr];
#pragma unroll
                for (int r = 0; r < 4; ++r)
                    cls[(wm + i * 16 + lg * 4 + r) * 128 + wn + j * 16 + lr] =
                        f2b(gelu_f(acc[i][j][r] + bval));
            }
        __syncthreads();
#pragma unroll
        for (int p = 0; p < 8; ++p) {
            int row = p * 16 + (tid >> 4);
            int colc = (tid & 15) * 8;
            u16x8 val = *(const u16x8*)&cls[row * 128 + colc];
            *(u16x8*)&outb[(size_t)(m0 + row) * N + n0 + colc] = val;
        }
        return;
    }

#pragma unroll
    for (int i = 0; i < 4; ++i) {
#pragma unroll
        for (int j = 0; j < 4; ++j) {
            int col = n0 + wn + j * 16 + lr;
#pragma unroll
            for (int r = 0; r < 4; ++r) {
                int row = m0 + wm + i * 16 + lg * 4 + r;
                float v = acc[i][j][r];
                int nm = col / 768, c = col % 768;
                int hh = c >> 6, d = c & 63;
                int bb = row >> 10, t = row & 1023;
                ushort_t val = f2b(v);
                if (nm == 0)
                    outb [((((size_t)bb * H_ + hh) << 10) + t) * D_ + d] = val;
                else if (nm == 1)
                    outb2[((((size_t)bb * H_ + hh) << 10) + t) * D_ + d] = val;
                else
                    outb3[(((size_t)bb * H_ + hh) * D_ + d) * T_ + t] = val;
            }
        }
    }
}

// ---------------------------------------------------------------------------
// split-K GEMM (mlp2): same 128x128 3-ring structure, K-slice per blockIdx.y,
// wide full-line f32 PARTIAL store (no bias/resid) to part + y*M*N.
// Kfull = row stride; Klen = slice length.  192 blocks per slice.
// ---------------------------------------------------------------------------
__global__ __launch_bounds__(256) void k_gemm_split(
        const ushort_t* __restrict__ A, const ushort_t* __restrict__ BT,
        float* __restrict__ part, int M, int N, int Kfull, int Klen) {
    __shared__ __align__(16) ushort_t S[24576];
    const int tid = threadIdx.x;
    const int lane = tid & 63, wave = tid >> 6;
    const int lr = lane & 15, lg = lane >> 4;
    const int wm = (wave >> 1) * 64, wn = (wave & 1) * 64;

    const int bid = blockIdx.x;
    const int m_in = bid & 7;
    const int strip = (bid >> 3) & 3;
    const int ncol = bid >> 5;
    const int m0 = (strip * 8 + m_in) << 7;
    const int n0 = ncol << 7;
    const int kb = blockIdx.y * Klen;
    float* outf = part + (size_t)blockIdx.y * M * N;

    const int sr = wave * 16 + (lane >> 2);
    const int sc = (((lane & 3) ^ ((lane >> 3) & 3)) << 3);

    f32x4 acc[4][4];
#pragma unroll
    for (int i = 0; i < 4; ++i)
#pragma unroll
        for (int j = 0; j < 4; ++j) acc[i][j] = (f32x4){0.f, 0.f, 0.f, 0.f};

    auto stage = [&](int k0, int buf) {
        ushort_t* as = S + buf * 4096;
        ushort_t* bs = S + 12288 + buf * 4096;
        gload16(&A [(size_t)(m0 + sr)      * Kfull + kb + k0 + sc], as + (wave * 16) * 32);
        gload16(&A [(size_t)(m0 + 64 + sr) * Kfull + kb + k0 + sc], as + (64 + wave * 16) * 32);
        gload16(&BT[(size_t)(n0 + sr)      * Kfull + kb + k0 + sc], bs + (wave * 16) * 32);
        gload16(&BT[(size_t)(n0 + 64 + sr) * Kfull + kb + k0 + sc], bs + (64 + wave * 16) * 32);
    };

    const int nt = Klen >> 5;
    stage(0, 0);
    stage(32, 1);
    int cur = 0, pre = 2;
    const int swzr = (lr >> 1) & 3;
    for (int t = 0; t < nt; ++t) {
        if (t + 1 < nt) asm volatile("s_waitcnt vmcnt(4)" ::: "memory");
        else            asm volatile("s_waitcnt vmcnt(0)" ::: "memory");
        __builtin_amdgcn_sched_barrier(0);
        __builtin_amdgcn_s_barrier();
        const ushort_t* as = S + cur * 4096;
        const ushort_t* bs = S + 12288 + cur * 4096;
        bf16x8 af[4], bfr[4];
#pragma unroll
        for (int i = 0; i < 4; ++i)
            af[i]  = *(const bf16x8*)&as[(wm + i * 16 + lr) * 32 + ((lg ^ swzr) << 3)];
#pragma unroll
        for (int j = 0; j < 4; ++j)
            bfr[j] = *(const bf16x8*)&bs[(wn + j * 16 + lr) * 32 + ((lg ^ swzr) << 3)];
        if (t + 2 < nt) stage((t + 2) << 5, pre);
#pragma unroll
        for (int i = 0; i < 4; ++i)
#pragma unroll
            for (int j = 0; j < 4; ++j)
                acc[i][j] = __builtin_amdgcn_mfma_f32_16x16x32_bf16(af[i], bfr[j], acc[i][j], 0, 0, 0);
        cur = (cur == 2) ? 0 : cur + 1;
        pre = (pre == 2) ? 0 : pre + 1;
    }

    float* cls = (float*)S;                           // [64][128] f32 = 32KB
#pragma unroll
    for (int h = 0; h < 2; ++h) {
        __syncthreads();
        if ((wm >> 6) == h) {
#pragma unroll
            for (int i = 0; i < 4; ++i)
#pragma unroll
                for (int j = 0; j < 4; ++j)
#pragma unroll
                    for (int r = 0; r < 4; ++r)
                        cls[(i * 16 + lg * 4 + r) * 128 + wn + j * 16 + lr] = acc[i][j][r];
        }
        __syncthreads();
#pragma unroll
        for (int p = 0; p < 8; ++p) {
            int row = p * 8 + (tid >> 5);
            int colc = (tid & 31) * 4;
            f32x4 val = *(const f32x4*)&cls[row * 128 + colc];
            *(f32x4*)&outf[(size_t)(m0 + h * 64 + row) * N + n0 + colc] = val;
        }
    }
}

// ---------------------------------------------------------------------------
// split-K reduce: x[i] += bias[col] + p0[i] + p1[i]   (f32, deterministic)
// ---------------------------------------------------------------------------
__global__ __launch_bounds__(256) void k_red2(float* __restrict__ x,
        const float* __restrict__ part, const float* __restrict__ bias) {
    const size_t stride = (size_t)4096 * C_;
    int i = (blockIdx.x * 256 + threadIdx.x) * 4;
    int col = i % C_;
    f32x4 xv = *(const f32x4*)&x[i];
    f32x4 bv = *(const f32x4*)&bias[col];
    f32x4 p0 = *(const f32x4*)&part[i];
    f32x4 p1 = *(const f32x4*)&part[stride + i];
    xv = xv + bv + p0 + p1;
    *(f32x4*)&x[i] = xv;
}

// ---------------------------------------------------------------------------
// flash attention, swapped-QK^T softmax (S^T = mfma(K,Q): scalar ls, 2-shfl
// reduce), KVBLK=128, no online max, P packed via v_cvt_pk_bf16_f32.
// ---------------------------------------------------------------------------
__global__ __launch_bounds__(256) void k_attn(const ushort_t* __restrict__ q,
        const ushort_t* __restrict__ k, const ushort_t* __restrict__ vT,
        ushort_t* __restrict__ yc) {
    __shared__ __align__(16) ushort_t P[4][16 * 136];
    const int lane = threadIdx.x & 63, wave = threadIdx.x >> 6;
    const int lr = lane & 15, lg = lane >> 4;
    const int bh = blockIdx.x;
    const int bb = bh / H_, hh = bh % H_;
    const int qrow0 = (gridDim.y - 1 - blockIdx.y) * 64 + wave * 16;
    const ushort_t* qb = q + (size_t)bh * T_ * D_;
    const ushort_t* kb = k + (size_t)bh * T_ * D_;
    const ushort_t* vb = vT + (size_t)bh * D_ * T_;

    bf16x8 aq0 = *(const bf16x8*)&qb[(qrow0 + lr) * D_ + lg * 8];
    bf16x8 aq1 = *(const bf16x8*)&qb[(qrow0 + lr) * D_ + 32 + lg * 8];

    f32x4 accY[4];
    float ls = 0.f;
#pragma unroll
    for (int d = 0; d < 4; ++d) accY[d] = (f32x4){0.f, 0.f, 0.f, 0.f};

    ushort_t* pw = &P[wave][0];
    const int kv_end = qrow0 + 16;
    for (int kv0 = 0; kv0 < kv_end; kv0 += 128) {
        const bool full = (kv0 + 127 <= qrow0);       // wave-uniform
        float p[8][4];
        float ps = 0.f;
#pragma unroll
        for (int j = 0; j < 8; ++j) {
            f32x4 s = (f32x4){0.f, 0.f, 0.f, 0.f};
            bf16x8 bk0 = *(const bf16x8*)&kb[(kv0 + j * 16 + lr) * D_ + lg * 8];
            bf16x8 bk1 = *(const bf16x8*)&kb[(kv0 + j * 16 + lr) * D_ + 32 + lg * 8];
            __builtin_amdgcn_s_setprio(1);
            s = __builtin_amdgcn_mfma_f32_16x16x32_bf16(bk0, aq0, s, 0, 0, 0);
            s = __builtin_amdgcn_mfma_f32_16x16x32_bf16(bk1, aq1, s, 0, 0, 0);
            __builtin_amdgcn_s_setprio(0);
            // lane holds S^T[k = kv0+j*16+lg*4+r][q = qrow0+lr]
            if (full) {
#pragma unroll
                for (int r = 0; r < 4; ++r) { p[j][r] = __expf(s[r] * 0.125f); ps += p[j][r]; }
            } else {
                int kcb = kv0 + j * 16 + lg * 4;
#pragma unroll
                for (int r = 0; r < 4; ++r) {
                    p[j][r] = (kcb + r <= qrow0 + lr) ? __expf(s[r] * 0.125f) : 0.f;
                    ps += p[j][r];
                }
            }
        }
        ps += __shfl_xor(ps, 16);
        ps += __shfl_xor(ps, 32);
        ls += ps;

        // previous iteration's pa reads must be complete before overwrite
        asm volatile("s_waitcnt lgkmcnt(0)" ::: "memory");
        __builtin_amdgcn_sched_barrier(0);
#pragma unroll
        for (int j = 0; j < 8; ++j) {
            unsigned int w0, w1;
            asm("v_cvt_pk_bf16_f32 %0, %1, %2" : "=v"(w0) : "v"(p[j][0]), "v"(p[j][1]));
            asm("v_cvt_pk_bf16_f32 %0, %1, %2" : "=v"(w1) : "v"(p[j][2]), "v"(p[j][3]));
            uint2 w; w.x = w0; w.y = w1;
            *(uint2*)&pw[lr * 136 + j * 16 + lg * 4] = w;
        }
        asm volatile("s_waitcnt lgkmcnt(0)" ::: "memory");
        __builtin_amdgcn_sched_barrier(0);
        bf16x8 pa[4];
#pragma unroll
        for (int ks = 0; ks < 4; ++ks)
            pa[ks] = *(const bf16x8*)&pw[lr * 136 + ks * 32 + lg * 8];
#pragma unroll
        for (int d = 0; d < 4; ++d) {
            __builtin_amdgcn_s_setprio(1);
#pragma unroll
            for (int ks = 0; ks < 4; ++ks) {
                bf16x8 bv = *(const bf16x8*)&vb[(d * 16 + lr) * T_ + kv0 + ks * 32 + lg * 8];
                accY[d] = __builtin_amdgcn_mfma_f32_16x16x32_bf16(pa[ks], bv, accY[d], 0, 0, 0);
            }
            __builtin_amdgcn_s_setprio(0);
        }
    }
    float inv[4];
#pragma unroll
    for (int r = 0; r < 4; ++r) inv[r] = 1.0f / __shfl(ls, lg * 4 + r);
#pragma unroll
    for (int d = 0; d < 4; ++d)
#pragma unroll
        for (int r = 0; r < 4; ++r) {
            int row = qrow0 + lg * 4 + r;
            yc[((size_t)bb * T_ + row) * C_ + hh * D_ + d * 16 + lr] = f2b(accY[d][r] * inv[r]);
        }
}

// ---------------------------------------------------------------------------
extern "C" void kernel_launch(void* const* d_in, const int* in_sizes, int n_in,
                              void* d_out, int out_size, void* d_ws, size_t ws_size,
                              hipStream_t stream) {
    (void)in_sizes; (void)n_in; (void)out_size; (void)ws_size;
    const int*   idx  = (const int*)d_in[0];
    const float* tok  = (const float*)d_in[1];
    const float* pos  = (const float*)d_in[2];
    const float* Wq   = (const float*)d_in[3];
    const float* Wk   = (const float*)d_in[4];
    const float* Wv   = (const float*)d_in[5];
    const float* Wp   = (const float*)d_in[6];
    const float* bp   = (const float*)d_in[7];
    const float* ln1s = (const float*)d_in[8];
    const float* ln1b = (const float*)d_in[9];
    const float* ln2s = (const float*)d_in[10];
    const float* ln2b = (const float*)d_in[11];
    const float* W1   = (const float*)d_in[12];
    const float* b1   = (const float*)d_in[13];
    const float* W2   = (const float*)d_in[14];
    const float* b2   = (const float*)d_in[15];
    const float* lnfs = (const float*)d_in[16];
    const float* lnfb = (const float*)d_in[17];
    const float* Wh   = (const float*)d_in[18];
    float* out = (float*)d_out;

    char* ws = (char*)d_ws;
    size_t off = 0;
    auto alloc = [&](size_t bytes) { void* p = ws + off; off += (bytes + 255) & ~(size_t)255; return p; };

    const size_t CCE = (size_t)C_ * C_;
    const size_t CFE = (size_t)C_ * F_;
    ushort_t* wCC  = (ushort_t*)alloc(16 * CCE * 2);
    ushort_t* w1T  = (ushort_t*)alloc((size_t)L_ * CFE * 2);
    ushort_t* w2T  = (ushort_t*)alloc((size_t)L_ * CFE * 2);
    ushort_t* whT  = (ushort_t*)alloc((size_t)C_ * V_ * 2);
    float*    x    = (float*)   alloc((size_t)B_ * T_ * C_ * 4);
    ushort_t* h    = (ushort_t*)alloc((size_t)B_ * T_ * C_ * 2);
    ushort_t* qb_  = (ushort_t*)alloc((size_t)B_ * T_ * C_ * 2);
    ushort_t* kb_  = (ushort_t*)alloc((size_t)B_ * T_ * C_ * 2);
    ushort_t* vTb  = (ushort_t*)alloc((size_t)B_ * T_ * C_ * 2);
    ushort_t* yc   = (ushort_t*)alloc((size_t)B_ * T_ * C_ * 2);
    ushort_t* mh   = (ushort_t*)alloc((size_t)B_ * T_ * F_ * 2);
    // split-K partials alias the dead qb_..yc region (25.2MB, exactly 2*M*C f32)
    float* part = (float*)qb_;

    dim3 tb(32, 8);
    k_tcvt16<<<dim3(24, 24, 16), tb, 0, stream>>>(Wq, Wk, Wv, Wp, wCC);
    k_tcvt<<<dim3(96, 24, 4), tb, 0, stream>>>(W1, w1T, C_, F_);
    k_tcvt<<<dim3(24, 96, 4), tb, 0, stream>>>(W2, w2T, F_, C_);
    k_tcvt<<<dim3(1000, 24, 1), tb, 0, stream>>>(Wh, whT, C_, V_);

    k_embed<<<3072, 256, 0, stream>>>(idx, tok, pos, x);

    for (int l = 0; l < L_; ++l) {
        k_ln<<<1024, 256, 0, stream>>>(x, ln1s + l * C_, ln1b + l * C_, h);
        k_gemm<3><<<18 * 32, 256, 0, stream>>>(h, wCC + (size_t)(l * 4) * CCE,
            nullptr, nullptr, nullptr, qb_, kb_, vTb, 4096, 3 * C_, C_);
        k_attn<<<dim3(48, 16), 256, 0, stream>>>(qb_, kb_, vTb, yc);
        k_gemm<2><<<6 * 32, 256, 0, stream>>>(yc, wCC + (size_t)(l * 4 + 3) * CCE,
            bp + l * C_, x, x, nullptr, nullptr, nullptr, 4096, C_, C_);
        k_ln<<<1024, 256, 0, stream>>>(x, ln2s + l * C_, ln2b + l * C_, h);
        k_gemm<1><<<24 * 32, 256, 0, stream>>>(h, w1T + (size_t)l * CFE,
            b1 + l * F_, nullptr, nullptr, mh, nullptr, nullptr, 4096, F_, C_);
        // mlp2 split-K=2: partials into dead qb_..yc region, then reduce
        k_gemm_split<<<dim3(6 * 32, 2), 256, 0, stream>>>(mh, w2T + (size_t)l * CFE,
            part, 4096, C_, F_, F_ / 2);
        k_red2<<<3072, 256, 0, stream>>>(x, part, b2 + l * C_);
    }
    k_ln<<<1024, 256, 0, stream>>>(x, lnfs, lnfb, h);
    k_gemm<0><<<250 * 32, 256, 0, stream>>>(h, whT, nullptr, nullptr,
        out, nullptr, nullptr, nullptr, 4096, V_, C_);
}

// Round 15
// 1083.845 us; speedup vs baseline: 1.0183x; 1.0183x over previous
//
#include <hip/hip_runtime.h>
#include <stdint.h>

// ---- problem constants (fixed by the reference) ----
#define B_ 4
#define T_ 1024
#define C_ 768
#define H_ 12
#define D_ 64
#define F_ 3072
#define V_ 32000
#define L_ 4

typedef unsigned short ushort_t;
typedef __bf16 bf16x8 __attribute__((ext_vector_type(8)));
typedef float f32x4 __attribute__((ext_vector_type(4)));
typedef unsigned short u16x8 __attribute__((ext_vector_type(8)));

__device__ __forceinline__ float b2f(unsigned short u) {
    union { unsigned int i; float f; } x; x.i = ((unsigned int)u) << 16; return x.f;
}
__device__ __forceinline__ unsigned short f2b(float f) {
    union { float f; unsigned int i; } x; x.f = f;
    unsigned int r = x.i + 0x7FFFu + ((x.i >> 16) & 1u);
    return (unsigned short)(r >> 16);
}

// fast exact-GELU: erf via Abramowitz-Stegun 7.1.26 (|eps| <= 1.5e-7)
__device__ __forceinline__ float gelu_f(float u) {
    float z = fabsf(u) * 0.70710678118654752f;
    float t = __builtin_amdgcn_rcpf(1.0f + 0.3275911f * z);
    float poly = t * (0.254829592f + t * (-0.284496736f + t * (1.421413741f +
                 t * (-1.453152027f + t * 1.061405429f))));
    float erfz = 1.0f - poly * __expf(-z * z);
    return u * 0.5f * (1.0f + copysignf(erfz, u));
}

// async global->LDS, 16B per lane; LDS dest = wave-uniform base, HW scatters lane*16B
__device__ __forceinline__ void gload16(const ushort_t* g, ushort_t* l) {
    __builtin_amdgcn_global_load_lds(
        (const __attribute__((address_space(1))) unsigned int*)g,
        (__attribute__((address_space(3))) unsigned int*)l, 16, 0, 0);
}

// ---------------------------------------------------------------------------
// embedding: x (bf16) = tok_emb[idx] + pos_emb
// ---------------------------------------------------------------------------
__global__ __launch_bounds__(256) void k_embed(const int* __restrict__ idx,
        const float* __restrict__ tok, const float* __restrict__ pos,
        ushort_t* __restrict__ x) {
    int i = blockIdx.x * 256 + threadIdx.x;
    int m = i / (C_ / 4);
    int cc = (i % (C_ / 4)) * 4;
    int t = m & (T_ - 1);
    int tokid = idx[m];
    float4 te = *(const float4*)&tok[(size_t)tokid * C_ + cc];
    float4 pe = *(const float4*)&pos[(size_t)t * C_ + cc];
    ushort4 o;
    o.x = f2b(te.x + pe.x); o.y = f2b(te.y + pe.y);
    o.z = f2b(te.z + pe.z); o.w = f2b(te.w + pe.w);
    *(ushort4*)&x[(size_t)m * C_ + cc] = o;
}

// ---------------------------------------------------------------------------
// LayerNorm: bf16 in -> bf16 out.  one ROW per WAVE, 4 rows/block.
// ---------------------------------------------------------------------------
__global__ __launch_bounds__(256) void k_ln(const ushort_t* __restrict__ x,
        const float* __restrict__ s, const float* __restrict__ b,
        ushort_t* __restrict__ out) {
    const int lane = threadIdx.x & 63, wave = threadIdx.x >> 6;
    const int row = blockIdx.x * 4 + wave;
    const ushort_t* xr = x + (size_t)row * C_;
    float vf[3][4];
    float sum = 0.f, sq = 0.f;
#pragma unroll
    for (int j = 0; j < 3; ++j) {
        ushort4 u = *(const ushort4*)&xr[lane * 4 + j * 256];
        vf[j][0] = b2f(u.x); vf[j][1] = b2f(u.y); vf[j][2] = b2f(u.z); vf[j][3] = b2f(u.w);
#pragma unroll
        for (int e = 0; e < 4; ++e) { sum += vf[j][e]; sq += vf[j][e] * vf[j][e]; }
    }
#pragma unroll
    for (int off = 1; off < 64; off <<= 1) {
        sum += __shfl_xor(sum, off);
        sq  += __shfl_xor(sq,  off);
    }
    float mean = sum * (1.f / C_);
    float var  = sq * (1.f / C_) - mean * mean;
    float rstd = rsqrtf(var + 1e-5f);
#pragma unroll
    for (int j = 0; j < 3; ++j) {
        int c = lane * 4 + j * 256;
        float4 sv = *(const float4*)&s[c];
        float4 bv = *(const float4*)&b[c];
        ushort4 o;
        o.x = f2b((vf[j][0] - mean) * rstd * sv.x + bv.x);
        o.y = f2b((vf[j][1] - mean) * rstd * sv.y + bv.y);
        o.z = f2b((vf[j][2] - mean) * rstd * sv.z + bv.z);
        o.w = f2b((vf[j][3] - mean) * rstd * sv.w + bv.w);
        *(ushort4*)&out[(size_t)row * C_ + c] = o;
    }
}

// ---------------------------------------------------------------------------
// batched weight transpose+convert: f32 [R,C] -> bf16 [C,R]
// ---------------------------------------------------------------------------
__global__ void k_tcvt(const float* __restrict__ in, ushort_t* __restrict__ out,
                       int R, int C) {
    __shared__ float tile[32][33];
    const float* src = in + (size_t)blockIdx.z * R * C;
    ushort_t* dst = out + (size_t)blockIdx.z * R * C;
    int r0 = blockIdx.y * 32, c0 = blockIdx.x * 32;
    int tx = threadIdx.x, ty = threadIdx.y;
#pragma unroll
    for (int i = ty; i < 32; i += 8)
        tile[i][tx] = src[(size_t)(r0 + i) * C + c0 + tx];
    __syncthreads();
#pragma unroll
    for (int i = ty; i < 32; i += 8)
        dst[(size_t)(c0 + i) * R + r0 + tx] = f2b(tile[tx][i]);
}

__global__ void k_tcvt16(const float* __restrict__ wq, const float* __restrict__ wk,
                         const float* __restrict__ wv, const float* __restrict__ wp,
                         ushort_t* __restrict__ out) {
    __shared__ float tile[32][33];
    int l = blockIdx.z >> 2, w = blockIdx.z & 3;
    const float* src = (w == 0 ? wq : w == 1 ? wk : w == 2 ? wv : wp) + (size_t)l * C_ * C_;
    ushort_t* dst = out + (size_t)blockIdx.z * C_ * C_;
    int r0 = blockIdx.y * 32, c0 = blockIdx.x * 32;
    int tx = threadIdx.x, ty = threadIdx.y;
#pragma unroll
    for (int i = ty; i < 32; i += 8)
        tile[i][tx] = src[(size_t)(r0 + i) * C_ + c0 + tx];
    __syncthreads();
#pragma unroll
    for (int i = ty; i < 32; i += 8)
        dst[(size_t)(c0 + i) * C_ + r0 + tx] = f2b(tile[tx][i]);
}

// ---------------------------------------------------------------------------
// GEMM 128x128: BK=32, 4 waves, 3-buffer ring, counted vmcnt(4),
// slot-XOR swizzle, supertile order, one barrier per K-step.
// EPI: 0 = f32 NT wide store (head)  1 = +bias GELU wide bf16
//      2 = +bias +resid(bf16 outb2), bf16 wide store to outb (in-place x ok)
//      3 = QKV scatter
// ---------------------------------------------------------------------------
template <int EPI>
__global__ __launch_bounds__(256) void k_gemm(
        const ushort_t* __restrict__ A, const ushort_t* __restrict__ BT,
        const float* __restrict__ bias, const float* __restrict__ resid,
        float* __restrict__ outf, ushort_t* __restrict__ outb,
        ushort_t* __restrict__ outb2, ushort_t* __restrict__ outb3,
        int M, int N, int K) {
    __shared__ __align__(16) ushort_t S[24576];
    const int tid = threadIdx.x;
    const int lane = tid & 63, wave = tid >> 6;
    const int lr = lane & 15, lg = lane >> 4;
    const int wm = (wave >> 1) * 64, wn = (wave & 1) * 64;

    const int bid = blockIdx.x;
    const int m_in = bid & 7;
    const int strip = (bid >> 3) & 3;
    const int ncol = bid >> 5;
    const int m0 = (strip * 8 + m_in) << 7;
    const int n0 = ncol << 7;

    const int sr = wave * 16 + (lane >> 2);
    const int sc = (((lane & 3) ^ ((lane >> 3) & 3)) << 3);

    f32x4 acc[4][4];
#pragma unroll
    for (int i = 0; i < 4; ++i)
#pragma unroll
        for (int j = 0; j < 4; ++j) acc[i][j] = (f32x4){0.f, 0.f, 0.f, 0.f};

    auto stage = [&](int k0, int buf) {
        ushort_t* as = S + buf * 4096;
        ushort_t* bs = S + 12288 + buf * 4096;
        gload16(&A [(size_t)(m0 + sr)      * K + k0 + sc], as + (wave * 16) * 32);
        gload16(&A [(size_t)(m0 + 64 + sr) * K + k0 + sc], as + (64 + wave * 16) * 32);
        gload16(&BT[(size_t)(n0 + sr)      * K + k0 + sc], bs + (wave * 16) * 32);
        gload16(&BT[(size_t)(n0 + 64 + sr) * K + k0 + sc], bs + (64 + wave * 16) * 32);
    };

    const int nt = K >> 5;
    stage(0, 0);
    stage(32, 1);
    int cur = 0, pre = 2;
    const int swzr = (lr >> 1) & 3;
    for (int t = 0; t < nt; ++t) {
        if (t + 1 < nt) asm volatile("s_waitcnt vmcnt(4)" ::: "memory");
        else            asm volatile("s_waitcnt vmcnt(0)" ::: "memory");
        __builtin_amdgcn_sched_barrier(0);
        __builtin_amdgcn_s_barrier();
        const ushort_t* as = S + cur * 4096;
        const ushort_t* bs = S + 12288 + cur * 4096;
        bf16x8 af[4], bfr[4];
#pragma unroll
        for (int i = 0; i < 4; ++i)
            af[i]  = *(const bf16x8*)&as[(wm + i * 16 + lr) * 32 + ((lg ^ swzr) << 3)];
#pragma unroll
        for (int j = 0; j < 4; ++j)
            bfr[j] = *(const bf16x8*)&bs[(wn + j * 16 + lr) * 32 + ((lg ^ swzr) << 3)];
        if (t + 2 < nt) stage((t + 2) << 5, pre);
#pragma unroll
        for (int i = 0; i < 4; ++i)
#pragma unroll
            for (int j = 0; j < 4; ++j)
                acc[i][j] = __builtin_amdgcn_mfma_f32_16x16x32_bf16(af[i], bfr[j], acc[i][j], 0, 0, 0);
        cur = (cur == 2) ? 0 : cur + 1;
        pre = (pre == 2) ? 0 : pre + 1;
    }

    if (EPI == 0) {
        float* cls = (float*)S;                       // [64][128] f32 = 32KB
#pragma unroll
        for (int h = 0; h < 2; ++h) {
            __syncthreads();
            if ((wm >> 6) == h) {
#pragma unroll
                for (int i = 0; i < 4; ++i)
#pragma unroll
                    for (int j = 0; j < 4; ++j)
#pragma unroll
                        for (int r = 0; r < 4; ++r)
                            cls[(i * 16 + lg * 4 + r) * 128 + wn + j * 16 + lr] = acc[i][j][r];
            }
            __syncthreads();
#pragma unroll
            for (int p = 0; p < 8; ++p) {
                int row = p * 8 + (tid >> 5);
                int colc = (tid & 31) * 4;
                f32x4 val = *(const f32x4*)&cls[row * 128 + colc];
                size_t gidx = (size_t)(m0 + h * 64 + row) * N + n0 + colc;
                __builtin_nontemporal_store(val, (f32x4*)&outf[gidx]);
            }
        }
        return;
    }

    if (EPI == 2) {
        // +bias +bf16 resid (outb2), wide bf16 stores to outb (in-place x ok)
        float* cls = (float*)S;                       // [64][128] f32 = 32KB
#pragma unroll
        for (int h = 0; h < 2; ++h) {
            __syncthreads();
            if ((wm >> 6) == h) {
#pragma unroll
                for (int i = 0; i < 4; ++i)
#pragma unroll
                    for (int j = 0; j < 4; ++j)
#pragma unroll
                        for (int r = 0; r < 4; ++r)
                            cls[(i * 16 + lg * 4 + r) * 128 + wn + j * 16 + lr] = acc[i][j][r];
            }
            __syncthreads();
#pragma unroll
            for (int p = 0; p < 4; ++p) {
                int idx = p * 256 + tid;
                int row = idx >> 4;
                int colc = (idx & 15) * 8;
                f32x4 v0 = *(const f32x4*)&cls[row * 128 + colc];
                f32x4 v1 = *(const f32x4*)&cls[row * 128 + colc + 4];
                size_t gidx = (size_t)(m0 + h * 64 + row) * N + n0 + colc;
                u16x8 rv = *(const u16x8*)&outb2[gidx];
                f32x4 b0 = *(const f32x4*)&bias[n0 + colc];
                f32x4 b1 = *(const f32x4*)&bias[n0 + colc + 4];
                u16x8 o;
#pragma unroll
                for (int e = 0; e < 4; ++e) o[e]     = f2b(v0[e] + b0[e] + b2f(rv[e]));
#pragma unroll
                for (int e = 0; e < 4; ++e) o[4 + e] = f2b(v1[e] + b1[e] + b2f(rv[4 + e]));
                *(u16x8*)&outb[gidx] = o;
            }
        }
        return;
    }

    if (EPI == 1) {
        ushort_t* cls = S;                            // [128][128] bf16 = 32KB
        __syncthreads();
#pragma unroll
        for (int i = 0; i < 4; ++i)
#pragma unroll
            for (int j = 0; j < 4; ++j) {
                float bval = bias[n0 + wn + j * 16 + lr];
#pragma unroll
                for (int r = 0; r < 4; ++r)
                    cls[(wm + i * 16 + lg * 4 + r) * 128 + wn + j * 16 + lr] =
                        f2b(gelu_f(acc[i][j][r] + bval));
            }
        __syncthreads();
#pragma unroll
        for (int p = 0; p < 8; ++p) {
            int row = p * 16 + (tid >> 4);
            int colc = (tid & 15) * 8;
            u16x8 val = *(const u16x8*)&cls[row * 128 + colc];
            *(u16x8*)&outb[(size_t)(m0 + row) * N + n0 + colc] = val;
        }
        return;
    }

#pragma unroll
    for (int i = 0; i < 4; ++i) {
#pragma unroll
        for (int j = 0; j < 4; ++j) {
            int col = n0 + wn + j * 16 + lr;
#pragma unroll
            for (int r = 0; r < 4; ++r) {
                int row = m0 + wm + i * 16 + lg * 4 + r;
                float v = acc[i][j][r];
                int nm = col / 768, c = col % 768;
                int hh = c >> 6, d = c & 63;
                int bb = row >> 10, t = row & 1023;
                ushort_t val = f2b(v);
                if (nm == 0)
                    outb [((((size_t)bb * H_ + hh) << 10) + t) * D_ + d] = val;
                else if (nm == 1)
                    outb2[((((size_t)bb * H_ + hh) << 10) + t) * D_ + d] = val;
                else
                    outb3[(((size_t)bb * H_ + hh) * D_ + d) * T_ + t] = val;
            }
        }
    }
}

// ---------------------------------------------------------------------------
// flash attention, swapped-QK^T softmax (S^T = mfma(K,Q): scalar ls, 2-shfl
// reduce), KVBLK=128, no online max, P packed via v_cvt_pk_bf16_f32.
// ---------------------------------------------------------------------------
__global__ __launch_bounds__(256) void k_attn(const ushort_t* __restrict__ q,
        const ushort_t* __restrict__ k, const ushort_t* __restrict__ vT,
        ushort_t* __restrict__ yc) {
    __shared__ __align__(16) ushort_t P[4][16 * 136];
    const int lane = threadIdx.x & 63, wave = threadIdx.x >> 6;
    const int lr = lane & 15, lg = lane >> 4;
    const int bh = blockIdx.x;
    const int bb = bh / H_, hh = bh % H_;
    const int qrow0 = (gridDim.y - 1 - blockIdx.y) * 64 + wave * 16;
    const ushort_t* qb = q + (size_t)bh * T_ * D_;
    const ushort_t* kb = k + (size_t)bh * T_ * D_;
    const ushort_t* vb = vT + (size_t)bh * D_ * T_;

    bf16x8 aq0 = *(const bf16x8*)&qb[(qrow0 + lr) * D_ + lg * 8];
    bf16x8 aq1 = *(const bf16x8*)&qb[(qrow0 + lr) * D_ + 32 + lg * 8];

    f32x4 accY[4];
    float ls = 0.f;
#pragma unroll
    for (int d = 0; d < 4; ++d) accY[d] = (f32x4){0.f, 0.f, 0.f, 0.f};

    ushort_t* pw = &P[wave][0];
    const int kv_end = qrow0 + 16;
    for (int kv0 = 0; kv0 < kv_end; kv0 += 128) {
        const bool full = (kv0 + 127 <= qrow0);       // wave-uniform
        float p[8][4];
        float ps = 0.f;
#pragma unroll
        for (int j = 0; j < 8; ++j) {
            f32x4 s = (f32x4){0.f, 0.f, 0.f, 0.f};
            bf16x8 bk0 = *(const bf16x8*)&kb[(kv0 + j * 16 + lr) * D_ + lg * 8];
            bf16x8 bk1 = *(const bf16x8*)&kb[(kv0 + j * 16 + lr) * D_ + 32 + lg * 8];
            __builtin_amdgcn_s_setprio(1);
            s = __builtin_amdgcn_mfma_f32_16x16x32_bf16(bk0, aq0, s, 0, 0, 0);
            s = __builtin_amdgcn_mfma_f32_16x16x32_bf16(bk1, aq1, s, 0, 0, 0);
            __builtin_amdgcn_s_setprio(0);
            // lane holds S^T[k = kv0+j*16+lg*4+r][q = qrow0+lr]
            if (full) {
#pragma unroll
                for (int r = 0; r < 4; ++r) { p[j][r] = __expf(s[r] * 0.125f); ps += p[j][r]; }
            } else {
                int kcb = kv0 + j * 16 + lg * 4;
#pragma unroll
                for (int r = 0; r < 4; ++r) {
                    p[j][r] = (kcb + r <= qrow0 + lr) ? __expf(s[r] * 0.125f) : 0.f;
                    ps += p[j][r];
                }
            }
        }
        ps += __shfl_xor(ps, 16);
        ps += __shfl_xor(ps, 32);
        ls += ps;

        // previous iteration's pa reads must be complete before overwrite
        asm volatile("s_waitcnt lgkmcnt(0)" ::: "memory");
        __builtin_amdgcn_sched_barrier(0);
#pragma unroll
        for (int j = 0; j < 8; ++j) {
            unsigned int w0, w1;
            asm("v_cvt_pk_bf16_f32 %0, %1, %2" : "=v"(w0) : "v"(p[j][0]), "v"(p[j][1]));
            asm("v_cvt_pk_bf16_f32 %0, %1, %2" : "=v"(w1) : "v"(p[j][2]), "v"(p[j][3]));
            uint2 w; w.x = w0; w.y = w1;
            *(uint2*)&pw[lr * 136 + j * 16 + lg * 4] = w;
        }
        asm volatile("s_waitcnt lgkmcnt(0)" ::: "memory");
        __builtin_amdgcn_sched_barrier(0);
        bf16x8 pa[4];
#pragma unroll
        for (int ks = 0; ks < 4; ++ks)
            pa[ks] = *(const bf16x8*)&pw[lr * 136 + ks * 32 + lg * 8];
#pragma unroll
        for (int d = 0; d < 4; ++d) {
            __builtin_amdgcn_s_setprio(1);
#pragma unroll
            for (int ks = 0; ks < 4; ++ks) {
                bf16x8 bv = *(const bf16x8*)&vb[(d * 16 + lr) * T_ + kv0 + ks * 32 + lg * 8];
                accY[d] = __builtin_amdgcn_mfma_f32_16x16x32_bf16(pa[ks], bv, accY[d], 0, 0, 0);
            }
            __builtin_amdgcn_s_setprio(0);
        }
    }
    float inv[4];
#pragma unroll
    for (int r = 0; r < 4; ++r) inv[r] = 1.0f / __shfl(ls, lg * 4 + r);
#pragma unroll
    for (int d = 0; d < 4; ++d)
#pragma unroll
        for (int r = 0; r < 4; ++r) {
            int row = qrow0 + lg * 4 + r;
            yc[((size_t)bb * T_ + row) * C_ + hh * D_ + d * 16 + lr] = f2b(accY[d][r] * inv[r]);
        }
}

// ---------------------------------------------------------------------------
extern "C" void kernel_launch(void* const* d_in, const int* in_sizes, int n_in,
                              void* d_out, int out_size, void* d_ws, size_t ws_size,
                              hipStream_t stream) {
    (void)in_sizes; (void)n_in; (void)out_size; (void)ws_size;
    const int*   idx  = (const int*)d_in[0];
    const float* tok  = (const float*)d_in[1];
    const float* pos  = (const float*)d_in[2];
    const float* Wq   = (const float*)d_in[3];
    const float* Wk   = (const float*)d_in[4];
    const float* Wv   = (const float*)d_in[5];
    const float* Wp   = (const float*)d_in[6];
    const float* bp   = (const float*)d_in[7];
    const float* ln1s = (const float*)d_in[8];
    const float* ln1b = (const float*)d_in[9];
    const float* ln2s = (const float*)d_in[10];
    const float* ln2b = (const float*)d_in[11];
    const float* W1   = (const float*)d_in[12];
    const float* b1   = (const float*)d_in[13];
    const float* W2   = (const float*)d_in[14];
    const float* b2   = (const float*)d_in[15];
    const float* lnfs = (const float*)d_in[16];
    const float* lnfb = (const float*)d_in[17];
    const float* Wh   = (const float*)d_in[18];
    float* out = (float*)d_out;

    char* ws = (char*)d_ws;
    size_t off = 0;
    auto alloc = [&](size_t bytes) { void* p = ws + off; off += (bytes + 255) & ~(size_t)255; return p; };

    const size_t CCE = (size_t)C_ * C_;
    const size_t CFE = (size_t)C_ * F_;
    ushort_t* wCC  = (ushort_t*)alloc(16 * CCE * 2);
    ushort_t* w1T  = (ushort_t*)alloc((size_t)L_ * CFE * 2);
    ushort_t* w2T  = (ushort_t*)alloc((size_t)L_ * CFE * 2);
    ushort_t* whT  = (ushort_t*)alloc((size_t)C_ * V_ * 2);
    ushort_t* x    = (ushort_t*)alloc((size_t)B_ * T_ * C_ * 2);   // bf16 residual stream
    ushort_t* h    = (ushort_t*)alloc((size_t)B_ * T_ * C_ * 2);
    ushort_t* qb_  = (ushort_t*)alloc((size_t)B_ * T_ * C_ * 2);
    ushort_t* kb_  = (ushort_t*)alloc((size_t)B_ * T_ * C_ * 2);
    ushort_t* vTb  = (ushort_t*)alloc((size_t)B_ * T_ * C_ * 2);
    ushort_t* yc   = (ushort_t*)alloc((size_t)B_ * T_ * C_ * 2);
    ushort_t* mh   = (ushort_t*)alloc((size_t)B_ * T_ * F_ * 2);

    dim3 tb(32, 8);
    k_tcvt16<<<dim3(24, 24, 16), tb, 0, stream>>>(Wq, Wk, Wv, Wp, wCC);
    k_tcvt<<<dim3(96, 24, 4), tb, 0, stream>>>(W1, w1T, C_, F_);
    k_tcvt<<<dim3(24, 96, 4), tb, 0, stream>>>(W2, w2T, F_, C_);
    k_tcvt<<<dim3(1000, 24, 1), tb, 0, stream>>>(Wh, whT, C_, V_);

    k_embed<<<3072, 256, 0, stream>>>(idx, tok, pos, x);

    for (int l = 0; l < L_; ++l) {
        k_ln<<<1024, 256, 0, stream>>>(x, ln1s + l * C_, ln1b + l * C_, h);
        k_gemm<3><<<18 * 32, 256, 0, stream>>>(h, wCC + (size_t)(l * 4) * CCE,
            nullptr, nullptr, nullptr, qb_, kb_, vTb, 4096, 3 * C_, C_);
        k_attn<<<dim3(48, 16), 256, 0, stream>>>(qb_, kb_, vTb, yc);
        k_gemm<2><<<6 * 32, 256, 0, stream>>>(yc, wCC + (size_t)(l * 4 + 3) * CCE,
            bp + l * C_, nullptr, nullptr, x, x, nullptr, 4096, C_, C_);
        k_ln<<<1024, 256, 0, stream>>>(x, ln2s + l * C_, ln2b + l * C_, h);
        k_gemm<1><<<24 * 32, 256, 0, stream>>>(h, w1T + (size_t)l * CFE,
            b1 + l * F_, nullptr, nullptr, mh, nullptr, nullptr, 4096, F_, C_);
        k_gemm<2><<<6 * 32, 256, 0, stream>>>(mh, w2T + (size_t)l * CFE,
            b2 + l * C_, nullptr, nullptr, x, x, nullptr, 4096, C_, F_);
    }
    k_ln<<<1024, 256, 0, stream>>>(x, lnfs, lnfb, h);
    k_gemm<0><<<250 * 32, 256, 0, stream>>>(h, whT, nullptr, nullptr,
        out, nullptr, nullptr, nullptr, 4096, V_, C_);
}

// Round 16
// 1064.752 us; speedup vs baseline: 1.0365x; 1.0179x over previous
//
#include <hip/hip_runtime.h>
#include <stdint.h>

// ---- problem constants (fixed by the reference) ----
#define B_ 4
#define T_ 1024
#define C_ 768
#define H_ 12
#define D_ 64
#define F_ 3072
#define V_ 32000
#define L_ 4

typedef unsigned short ushort_t;
typedef __bf16 bf16x8 __attribute__((ext_vector_type(8)));
typedef float f32x4 __attribute__((ext_vector_type(4)));
typedef unsigned short u16x8 __attribute__((ext_vector_type(8)));

__device__ __forceinline__ float b2f(unsigned short u) {
    union { unsigned int i; float f; } x; x.i = ((unsigned int)u) << 16; return x.f;
}
__device__ __forceinline__ unsigned short f2b(float f) {
    union { float f; unsigned int i; } x; x.f = f;
    unsigned int r = x.i + 0x7FFFu + ((x.i >> 16) & 1u);
    return (unsigned short)(r >> 16);
}

// fast exact-GELU: erf via Abramowitz-Stegun 7.1.26 (|eps| <= 1.5e-7)
__device__ __forceinline__ float gelu_f(float u) {
    float z = fabsf(u) * 0.70710678118654752f;
    float t = __builtin_amdgcn_rcpf(1.0f + 0.3275911f * z);
    float poly = t * (0.254829592f + t * (-0.284496736f + t * (1.421413741f +
                 t * (-1.453152027f + t * 1.061405429f))));
    float erfz = 1.0f - poly * __expf(-z * z);
    return u * 0.5f * (1.0f + copysignf(erfz, u));
}

// async global->LDS, 16B per lane; LDS dest = wave-uniform base, HW scatters lane*16B
__device__ __forceinline__ void gload16(const ushort_t* g, ushort_t* l) {
    __builtin_amdgcn_global_load_lds(
        (const __attribute__((address_space(1))) unsigned int*)g,
        (__attribute__((address_space(3))) unsigned int*)l, 16, 0, 0);
}

// ---------------------------------------------------------------------------
// embedding: x (bf16) = tok_emb[idx] + pos_emb
// ---------------------------------------------------------------------------
__global__ __launch_bounds__(256) void k_embed(const int* __restrict__ idx,
        const float* __restrict__ tok, const float* __restrict__ pos,
        ushort_t* __restrict__ x) {
    int i = blockIdx.x * 256 + threadIdx.x;
    int m = i / (C_ / 4);
    int cc = (i % (C_ / 4)) * 4;
    int t = m & (T_ - 1);
    int tokid = idx[m];
    float4 te = *(const float4*)&tok[(size_t)tokid * C_ + cc];
    float4 pe = *(const float4*)&pos[(size_t)t * C_ + cc];
    ushort4 o;
    o.x = f2b(te.x + pe.x); o.y = f2b(te.y + pe.y);
    o.z = f2b(te.z + pe.z); o.w = f2b(te.w + pe.w);
    *(ushort4*)&x[(size_t)m * C_ + cc] = o;
}

// ---------------------------------------------------------------------------
// LayerNorm: bf16 in -> bf16 out.  one ROW per WAVE, 4 rows/block.
// ---------------------------------------------------------------------------
__global__ __launch_bounds__(256) void k_ln(const ushort_t* __restrict__ x,
        const float* __restrict__ s, const float* __restrict__ b,
        ushort_t* __restrict__ out) {
    const int lane = threadIdx.x & 63, wave = threadIdx.x >> 6;
    const int row = blockIdx.x * 4 + wave;
    const ushort_t* xr = x + (size_t)row * C_;
    float vf[3][4];
    float sum = 0.f, sq = 0.f;
#pragma unroll
    for (int j = 0; j < 3; ++j) {
        ushort4 u = *(const ushort4*)&xr[lane * 4 + j * 256];
        vf[j][0] = b2f(u.x); vf[j][1] = b2f(u.y); vf[j][2] = b2f(u.z); vf[j][3] = b2f(u.w);
#pragma unroll
        for (int e = 0; e < 4; ++e) { sum += vf[j][e]; sq += vf[j][e] * vf[j][e]; }
    }
#pragma unroll
    for (int off = 1; off < 64; off <<= 1) {
        sum += __shfl_xor(sum, off);
        sq  += __shfl_xor(sq,  off);
    }
    float mean = sum * (1.f / C_);
    float var  = sq * (1.f / C_) - mean * mean;
    float rstd = rsqrtf(var + 1e-5f);
#pragma unroll
    for (int j = 0; j < 3; ++j) {
        int c = lane * 4 + j * 256;
        float4 sv = *(const float4*)&s[c];
        float4 bv = *(const float4*)&b[c];
        ushort4 o;
        o.x = f2b((vf[j][0] - mean) * rstd * sv.x + bv.x);
        o.y = f2b((vf[j][1] - mean) * rstd * sv.y + bv.y);
        o.z = f2b((vf[j][2] - mean) * rstd * sv.z + bv.z);
        o.w = f2b((vf[j][3] - mean) * rstd * sv.w + bv.w);
        *(ushort4*)&out[(size_t)row * C_ + c] = o;
    }
}

// ---------------------------------------------------------------------------
// batched weight transpose+convert: f32 [R,C] -> bf16 [C,R]
// ---------------------------------------------------------------------------
__global__ void k_tcvt(const float* __restrict__ in, ushort_t* __restrict__ out,
                       int R, int C) {
    __shared__ float tile[32][33];
    const float* src = in + (size_t)blockIdx.z * R * C;
    ushort_t* dst = out + (size_t)blockIdx.z * R * C;
    int r0 = blockIdx.y * 32, c0 = blockIdx.x * 32;
    int tx = threadIdx.x, ty = threadIdx.y;
#pragma unroll
    for (int i = ty; i < 32; i += 8)
        tile[i][tx] = src[(size_t)(r0 + i) * C + c0 + tx];
    __syncthreads();
#pragma unroll
    for (int i = ty; i < 32; i += 8)
        dst[(size_t)(c0 + i) * R + r0 + tx] = f2b(tile[tx][i]);
}

__global__ void k_tcvt16(const float* __restrict__ wq, const float* __restrict__ wk,
                         const float* __restrict__ wv, const float* __restrict__ wp,
                         ushort_t* __restrict__ out) {
    __shared__ float tile[32][33];
    int l = blockIdx.z >> 2, w = blockIdx.z & 3;
    const float* src = (w == 0 ? wq : w == 1 ? wk : w == 2 ? wv : wp) + (size_t)l * C_ * C_;
    ushort_t* dst = out + (size_t)blockIdx.z * C_ * C_;
    int r0 = blockIdx.y * 32, c0 = blockIdx.x * 32;
    int tx = threadIdx.x, ty = threadIdx.y;
#pragma unroll
    for (int i = ty; i < 32; i += 8)
        tile[i][tx] = src[(size_t)(r0 + i) * C_ + c0 + tx];
    __syncthreads();
#pragma unroll
    for (int i = ty; i < 32; i += 8)
        dst[(size_t)(c0 + i) * C_ + r0 + tx] = f2b(tile[tx][i]);
}

// ---------------------------------------------------------------------------
// GEMM 128x128 (mid GEMMs): BK=32, 4 waves, 3-buffer ring, counted vmcnt(4),
// slot-XOR swizzle, supertile order, one barrier per K-step.
// EPI: 1 = +bias GELU wide bf16
//      2 = +bias +resid(bf16 outb2), bf16 wide store to outb (in-place x ok)
//      3 = QKV scatter
// ---------------------------------------------------------------------------
template <int EPI>
__global__ __launch_bounds__(256) void k_gemm(
        const ushort_t* __restrict__ A, const ushort_t* __restrict__ BT,
        const float* __restrict__ bias, const float* __restrict__ resid,
        float* __restrict__ outf, ushort_t* __restrict__ outb,
        ushort_t* __restrict__ outb2, ushort_t* __restrict__ outb3,
        int M, int N, int K) {
    __shared__ __align__(16) ushort_t S[24576];
    const int tid = threadIdx.x;
    const int lane = tid & 63, wave = tid >> 6;
    const int lr = lane & 15, lg = lane >> 4;
    const int wm = (wave >> 1) * 64, wn = (wave & 1) * 64;

    const int bid = blockIdx.x;
    const int m_in = bid & 7;
    const int strip = (bid >> 3) & 3;
    const int ncol = bid >> 5;
    const int m0 = (strip * 8 + m_in) << 7;
    const int n0 = ncol << 7;

    const int sr = wave * 16 + (lane >> 2);
    const int sc = (((lane & 3) ^ ((lane >> 3) & 3)) << 3);

    f32x4 acc[4][4];
#pragma unroll
    for (int i = 0; i < 4; ++i)
#pragma unroll
        for (int j = 0; j < 4; ++j) acc[i][j] = (f32x4){0.f, 0.f, 0.f, 0.f};

    auto stage = [&](int k0, int buf) {
        ushort_t* as = S + buf * 4096;
        ushort_t* bs = S + 12288 + buf * 4096;
        gload16(&A [(size_t)(m0 + sr)      * K + k0 + sc], as + (wave * 16) * 32);
        gload16(&A [(size_t)(m0 + 64 + sr) * K + k0 + sc], as + (64 + wave * 16) * 32);
        gload16(&BT[(size_t)(n0 + sr)      * K + k0 + sc], bs + (wave * 16) * 32);
        gload16(&BT[(size_t)(n0 + 64 + sr) * K + k0 + sc], bs + (64 + wave * 16) * 32);
    };

    const int nt = K >> 5;
    stage(0, 0);
    stage(32, 1);
    int cur = 0, pre = 2;
    const int swzr = (lr >> 1) & 3;
    for (int t = 0; t < nt; ++t) {
        if (t + 1 < nt) asm volatile("s_waitcnt vmcnt(4)" ::: "memory");
        else            asm volatile("s_waitcnt vmcnt(0)" ::: "memory");
        __builtin_amdgcn_sched_barrier(0);
        __builtin_amdgcn_s_barrier();
        const ushort_t* as = S + cur * 4096;
        const ushort_t* bs = S + 12288 + cur * 4096;
        bf16x8 af[4], bfr[4];
#pragma unroll
        for (int i = 0; i < 4; ++i)
            af[i]  = *(const bf16x8*)&as[(wm + i * 16 + lr) * 32 + ((lg ^ swzr) << 3)];
#pragma unroll
        for (int j = 0; j < 4; ++j)
            bfr[j] = *(const bf16x8*)&bs[(wn + j * 16 + lr) * 32 + ((lg ^ swzr) << 3)];
        if (t + 2 < nt) stage((t + 2) << 5, pre);
#pragma unroll
        for (int i = 0; i < 4; ++i)
#pragma unroll
            for (int j = 0; j < 4; ++j)
                acc[i][j] = __builtin_amdgcn_mfma_f32_16x16x32_bf16(af[i], bfr[j], acc[i][j], 0, 0, 0);
        cur = (cur == 2) ? 0 : cur + 1;
        pre = (pre == 2) ? 0 : pre + 1;
    }

    if (EPI == 2) {
        // +bias +bf16 resid (outb2), wide bf16 stores to outb (in-place x ok)
        float* cls = (float*)S;                       // [64][128] f32 = 32KB
#pragma unroll
        for (int h = 0; h < 2; ++h) {
            __syncthreads();
            if ((wm >> 6) == h) {
#pragma unroll
                for (int i = 0; i < 4; ++i)
#pragma unroll
                    for (int j = 0; j < 4; ++j)
#pragma unroll
                        for (int r = 0; r < 4; ++r)
                            cls[(i * 16 + lg * 4 + r) * 128 + wn + j * 16 + lr] = acc[i][j][r];
            }
            __syncthreads();
#pragma unroll
            for (int p = 0; p < 4; ++p) {
                int idx = p * 256 + tid;
                int row = idx >> 4;
                int colc = (idx & 15) * 8;
                f32x4 v0 = *(const f32x4*)&cls[row * 128 + colc];
                f32x4 v1 = *(const f32x4*)&cls[row * 128 + colc + 4];
                size_t gidx = (size_t)(m0 + h * 64 + row) * N + n0 + colc;
                u16x8 rv = *(const u16x8*)&outb2[gidx];
                f32x4 b0 = *(const f32x4*)&bias[n0 + colc];
                f32x4 b1 = *(const f32x4*)&bias[n0 + colc + 4];
                u16x8 o;
#pragma unroll
                for (int e = 0; e < 4; ++e) o[e]     = f2b(v0[e] + b0[e] + b2f(rv[e]));
#pragma unroll
                for (int e = 0; e < 4; ++e) o[4 + e] = f2b(v1[e] + b1[e] + b2f(rv[4 + e]));
                *(u16x8*)&outb[gidx] = o;
            }
        }
        return;
    }

    if (EPI == 1) {
        ushort_t* cls = S;                            // [128][128] bf16 = 32KB
        __syncthreads();
#pragma unroll
        for (int i = 0; i < 4; ++i)
#pragma unroll
            for (int j = 0; j < 4; ++j) {
                float bval = bias[n0 + wn + j * 16 + lr];
#pragma unroll
                for (int r = 0; r < 4; ++r)
                    cls[(wm + i * 16 + lg * 4 + r) * 128 + wn + j * 16 + lr] =
                        f2b(gelu_f(acc[i][j][r] + bval));
            }
        __syncthreads();
#pragma unroll
        for (int p = 0; p < 8; ++p) {
            int row = p * 16 + (tid >> 4);
            int colc = (tid & 15) * 8;
            u16x8 val = *(const u16x8*)&cls[row * 128 + colc];
            *(u16x8*)&outb[(size_t)(m0 + row) * N + n0 + colc] = val;
        }
        return;
    }

#pragma unroll
    for (int i = 0; i < 4; ++i) {
#pragma unroll
        for (int j = 0; j < 4; ++j) {
            int col = n0 + wn + j * 16 + lr;
#pragma unroll
            for (int r = 0; r < 4; ++r) {
                int row = m0 + wm + i * 16 + lg * 4 + r;
                float v = acc[i][j][r];
                int nm = col / 768, c = col % 768;
                int hh = c >> 6, d = c & 63;
                int bb = row >> 10, t = row & 1023;
                ushort_t val = f2b(v);
                if (nm == 0)
                    outb [((((size_t)bb * H_ + hh) << 10) + t) * D_ + d] = val;
                else if (nm == 1)
                    outb2[((((size_t)bb * H_ + hh) << 10) + t) * D_ + d] = val;
                else
                    outb3[(((size_t)bb * H_ + hh) * D_ + d) * T_ + t] = val;
            }
        }
    }
}

// ---------------------------------------------------------------------------
// k_gemmh (head): 128x256 tile, 8 waves (2x4), BK=32, 3-ring (72KB LDS)
// -> 2 blocks/CU (16 waves/CU, 4/SIMD TLP).  3 gload16/wave/K-step, counted
// vmcnt(3), one barrier per K-step, slot-XOR swizzle (same algebra: all
// row-base terms are multiples of 16).  Supertile order, B read once.
// Wide NT f32 epilogue via LDS [64][260] (2-way ds_write = free).
// Requires M == 4096, N % 256 == 0 (head: N=32000 -> 4000 blocks).
// ---------------------------------------------------------------------------
__global__ __launch_bounds__(512, 4) void k_gemmh(
        const ushort_t* __restrict__ A, const ushort_t* __restrict__ BT,
        float* __restrict__ outf, int M, int N, int K) {
    __shared__ __align__(16) ushort_t S[36864];   // 72KB: A-ring 3x8KB | B-ring 3x16KB
    const int tid = threadIdx.x;
    const int lane = tid & 63, wave = tid >> 6;
    const int lr = lane & 15, lg = lane >> 4;
    const int wm = (wave >> 2) * 64, wn = (wave & 3) * 64;

    const int bid = blockIdx.x;
    const int m_in = bid & 7;
    const int strip = (bid >> 3) & 3;
    const int ncol = bid >> 5;
    const int m0 = (strip * 8 + m_in) << 7;
    const int n0 = ncol << 8;

    const int srr = lane >> 2;                    // row within 16-row chunk
    const int sc = (((lane & 3) ^ ((lane >> 3) & 3)) << 3);

    f32x4 acc[4][4];
#pragma unroll
    for (int i = 0; i < 4; ++i)
#pragma unroll
        for (int j = 0; j < 4; ++j) acc[i][j] = (f32x4){0.f, 0.f, 0.f, 0.f};

    auto stage = [&](int k0, int buf) {
        ushort_t* as = S + buf * 4096;
        ushort_t* bs = S + 12288 + buf * 8192;
        gload16(&A [(size_t)(m0 + wave * 16 + srr) * K + k0 + sc], as + (wave * 16) * 32);
        gload16(&BT[(size_t)(n0 + wave * 32 + srr)      * K + k0 + sc], bs + (wave * 32) * 32);
        gload16(&BT[(size_t)(n0 + wave * 32 + 16 + srr) * K + k0 + sc], bs + (wave * 32 + 16) * 32);
    };

    const int nt = K >> 5;                        // 24 for K=768
    stage(0, 0);
    stage(32, 1);
    int cur = 0, pre = 2;
    const int swzr = (lr >> 1) & 3;
    for (int t = 0; t < nt; ++t) {
        if (t + 1 < nt) asm volatile("s_waitcnt vmcnt(3)" ::: "memory");
        else            asm volatile("s_waitcnt vmcnt(0)" ::: "memory");
        __builtin_amdgcn_sched_barrier(0);
        __builtin_amdgcn_s_barrier();
        const ushort_t* as = S + cur * 4096;
        const ushort_t* bs = S + 12288 + cur * 8192;
        bf16x8 af[4], bfr[4];
#pragma unroll
        for (int i = 0; i < 4; ++i)
            af[i]  = *(const bf16x8*)&as[(wm + i * 16 + lr) * 32 + ((lg ^ swzr) << 3)];
#pragma unroll
        for (int j = 0; j < 4; ++j)
            bfr[j] = *(const bf16x8*)&bs[(wn + j * 16 + lr) * 32 + ((lg ^ swzr) << 3)];
        if (t + 2 < nt) stage((t + 2) << 5, pre);
#pragma unroll
        for (int i = 0; i < 4; ++i)
#pragma unroll
            for (int j = 0; j < 4; ++j)
                acc[i][j] = __builtin_amdgcn_mfma_f32_16x16x32_bf16(af[i], bfr[j], acc[i][j], 0, 0, 0);
        cur = (cur == 2) ? 0 : cur + 1;
        pre = (pre == 2) ? 0 : pre + 1;
    }

    // wide NT f32 epilogue: 2 passes of 64 rows x 256 cols, LDS [64][260] f32
    float* cls = (float*)S;
#pragma unroll
    for (int h = 0; h < 2; ++h) {
        __syncthreads();
        if ((wm >> 6) == h) {
#pragma unroll
            for (int i = 0; i < 4; ++i)
#pragma unroll
                for (int j = 0; j < 4; ++j)
#pragma unroll
                    for (int r = 0; r < 4; ++r)
                        cls[(i * 16 + lg * 4 + r) * 260 + wn + j * 16 + lr] = acc[i][j][r];
        }
        __syncthreads();
#pragma unroll
        for (int p = 0; p < 8; ++p) {
            int idx = p * 512 + tid;
            int row = idx >> 6;
            int colc = (idx & 63) * 4;
            f32x4 val = *(const f32x4*)&cls[row * 260 + colc];
            __builtin_nontemporal_store(val,
                (f32x4*)&outf[(size_t)(m0 + h * 64 + row) * N + n0 + colc]);
        }
    }
}

// ---------------------------------------------------------------------------
// flash attention, swapped-QK^T softmax (S^T = mfma(K,Q): scalar ls, 2-shfl
// reduce), KVBLK=128, no online max, P packed via v_cvt_pk_bf16_f32.
// ---------------------------------------------------------------------------
__global__ __launch_bounds__(256) void k_attn(const ushort_t* __restrict__ q,
        const ushort_t* __restrict__ k, const ushort_t* __restrict__ vT,
        ushort_t* __restrict__ yc) {
    __shared__ __align__(16) ushort_t P[4][16 * 136];
    const int lane = threadIdx.x & 63, wave = threadIdx.x >> 6;
    const int lr = lane & 15, lg = lane >> 4;
    const int bh = blockIdx.x;
    const int bb = bh / H_, hh = bh % H_;
    const int qrow0 = (gridDim.y - 1 - blockIdx.y) * 64 + wave * 16;
    const ushort_t* qb = q + (size_t)bh * T_ * D_;
    const ushort_t* kb = k + (size_t)bh * T_ * D_;
    const ushort_t* vb = vT + (size_t)bh * D_ * T_;

    bf16x8 aq0 = *(const bf16x8*)&qb[(qrow0 + lr) * D_ + lg * 8];
    bf16x8 aq1 = *(const bf16x8*)&qb[(qrow0 + lr) * D_ + 32 + lg * 8];

    f32x4 accY[4];
    float ls = 0.f;
#pragma unroll
    for (int d = 0; d < 4; ++d) accY[d] = (f32x4){0.f, 0.f, 0.f, 0.f};

    ushort_t* pw = &P[wave][0];
    const int kv_end = qrow0 + 16;
    for (int kv0 = 0; kv0 < kv_end; kv0 += 128) {
        const bool full = (kv0 + 127 <= qrow0);       // wave-uniform
        float p[8][4];
        float ps = 0.f;
#pragma unroll
        for (int j = 0; j < 8; ++j) {
            f32x4 s = (f32x4){0.f, 0.f, 0.f, 0.f};
            bf16x8 bk0 = *(const bf16x8*)&kb[(kv0 + j * 16 + lr) * D_ + lg * 8];
            bf16x8 bk1 = *(const bf16x8*)&kb[(kv0 + j * 16 + lr) * D_ + 32 + lg * 8];
            __builtin_amdgcn_s_setprio(1);
            s = __builtin_amdgcn_mfma_f32_16x16x32_bf16(bk0, aq0, s, 0, 0, 0);
            s = __builtin_amdgcn_mfma_f32_16x16x32_bf16(bk1, aq1, s, 0, 0, 0);
            __builtin_amdgcn_s_setprio(0);
            // lane holds S^T[k = kv0+j*16+lg*4+r][q = qrow0+lr]
            if (full) {
#pragma unroll
                for (int r = 0; r < 4; ++r) { p[j][r] = __expf(s[r] * 0.125f); ps += p[j][r]; }
            } else {
                int kcb = kv0 + j * 16 + lg * 4;
#pragma unroll
                for (int r = 0; r < 4; ++r) {
                    p[j][r] = (kcb + r <= qrow0 + lr) ? __expf(s[r] * 0.125f) : 0.f;
                    ps += p[j][r];
                }
            }
        }
        ps += __shfl_xor(ps, 16);
        ps += __shfl_xor(ps, 32);
        ls += ps;

        // previous iteration's pa reads must be complete before overwrite
        asm volatile("s_waitcnt lgkmcnt(0)" ::: "memory");
        __builtin_amdgcn_sched_barrier(0);
#pragma unroll
        for (int j = 0; j < 8; ++j) {
            unsigned int w0, w1;
            asm("v_cvt_pk_bf16_f32 %0, %1, %2" : "=v"(w0) : "v"(p[j][0]), "v"(p[j][1]));
            asm("v_cvt_pk_bf16_f32 %0, %1, %2" : "=v"(w1) : "v"(p[j][2]), "v"(p[j][3]));
            uint2 w; w.x = w0; w.y = w1;
            *(uint2*)&pw[lr * 136 + j * 16 + lg * 4] = w;
        }
        asm volatile("s_waitcnt lgkmcnt(0)" ::: "memory");
        __builtin_amdgcn_sched_barrier(0);
        bf16x8 pa[4];
#pragma unroll
        for (int ks = 0; ks < 4; ++ks)
            pa[ks] = *(const bf16x8*)&pw[lr * 136 + ks * 32 + lg * 8];
#pragma unroll
        for (int d = 0; d < 4; ++d) {
            __builtin_amdgcn_s_setprio(1);
#pragma unroll
            for (int ks = 0; ks < 4; ++ks) {
                bf16x8 bv = *(const bf16x8*)&vb[(d * 16 + lr) * T_ + kv0 + ks * 32 + lg * 8];
                accY[d] = __builtin_amdgcn_mfma_f32_16x16x32_bf16(pa[ks], bv, accY[d], 0, 0, 0);
            }
            __builtin_amdgcn_s_setprio(0);
        }
    }
    float inv[4];
#pragma unroll
    for (int r = 0; r < 4; ++r) inv[r] = 1.0f / __shfl(ls, lg * 4 + r);
#pragma unroll
    for (int d = 0; d < 4; ++d)
#pragma unroll
        for (int r = 0; r < 4; ++r) {
            int row = qrow0 + lg * 4 + r;
            yc[((size_t)bb * T_ + row) * C_ + hh * D_ + d * 16 + lr] = f2b(accY[d][r] * inv[r]);
        }
}

// ---------------------------------------------------------------------------
extern "C" void kernel_launch(void* const* d_in, const int* in_sizes, int n_in,
                              void* d_out, int out_size, void* d_ws, size_t ws_size,
                              hipStream_t stream) {
    (void)in_sizes; (void)n_in; (void)out_size; (void)ws_size;
    const int*   idx  = (const int*)d_in[0];
    const float* tok  = (const float*)d_in[1];
    const float* pos  = (const float*)d_in[2];
    const float* Wq   = (const float*)d_in[3];
    const float* Wk   = (const float*)d_in[4];
    const float* Wv   = (const float*)d_in[5];
    const float* Wp   = (const float*)d_in[6];
    const float* bp   = (const float*)d_in[7];
    const float* ln1s = (const float*)d_in[8];
    const float* ln1b = (const float*)d_in[9];
    const float* ln2s = (const float*)d_in[10];
    const float* ln2b = (const float*)d_in[11];
    const float* W1   = (const float*)d_in[12];
    const float* b1   = (const float*)d_in[13];
    const float* W2   = (const float*)d_in[14];
    const float* b2   = (const float*)d_in[15];
    const float* lnfs = (const float*)d_in[16];
    const float* lnfb = (const float*)d_in[17];
    const float* Wh   = (const float*)d_in[18];
    float* out = (float*)d_out;

    char* ws = (char*)d_ws;
    size_t off = 0;
    auto alloc = [&](size_t bytes) { void* p = ws + off; off += (bytes + 255) & ~(size_t)255; return p; };

    const size_t CCE = (size_t)C_ * C_;
    const size_t CFE = (size_t)C_ * F_;
    ushort_t* wCC  = (ushort_t*)alloc(16 * CCE * 2);
    ushort_t* w1T  = (ushort_t*)alloc((size_t)L_ * CFE * 2);
    ushort_t* w2T  = (ushort_t*)alloc((size_t)L_ * CFE * 2);
    ushort_t* whT  = (ushort_t*)alloc((size_t)C_ * V_ * 2);
    ushort_t* x    = (ushort_t*)alloc((size_t)B_ * T_ * C_ * 2);   // bf16 residual stream
    ushort_t* h    = (ushort_t*)alloc((size_t)B_ * T_ * C_ * 2);
    ushort_t* qb_  = (ushort_t*)alloc((size_t)B_ * T_ * C_ * 2);
    ushort_t* kb_  = (ushort_t*)alloc((size_t)B_ * T_ * C_ * 2);
    ushort_t* vTb  = (ushort_t*)alloc((size_t)B_ * T_ * C_ * 2);
    ushort_t* yc   = (ushort_t*)alloc((size_t)B_ * T_ * C_ * 2);
    ushort_t* mh   = (ushort_t*)alloc((size_t)B_ * T_ * F_ * 2);

    dim3 tb(32, 8);
    k_tcvt16<<<dim3(24, 24, 16), tb, 0, stream>>>(Wq, Wk, Wv, Wp, wCC);
    k_tcvt<<<dim3(96, 24, 4), tb, 0, stream>>>(W1, w1T, C_, F_);
    k_tcvt<<<dim3(24, 96, 4), tb, 0, stream>>>(W2, w2T, F_, C_);
    k_tcvt<<<dim3(1000, 24, 1), tb, 0, stream>>>(Wh, whT, C_, V_);

    k_embed<<<3072, 256, 0, stream>>>(idx, tok, pos, x);

    for (int l = 0; l < L_; ++l) {
        k_ln<<<1024, 256, 0, stream>>>(x, ln1s + l * C_, ln1b + l * C_, h);
        k_gemm<3><<<18 * 32, 256, 0, stream>>>(h, wCC + (size_t)(l * 4) * CCE,
            nullptr, nullptr, nullptr, qb_, kb_, vTb, 4096, 3 * C_, C_);
        k_attn<<<dim3(48, 16), 256, 0, stream>>>(qb_, kb_, vTb, yc);
        k_gemm<2><<<6 * 32, 256, 0, stream>>>(yc, wCC + (size_t)(l * 4 + 3) * CCE,
            bp + l * C_, nullptr, nullptr, x, x, nullptr, 4096, C_, C_);
        k_ln<<<1024, 256, 0, stream>>>(x, ln2s + l * C_, ln2b + l * C_, h);
        k_gemm<1><<<24 * 32, 256, 0, stream>>>(h, w1T + (size_t)l * CFE,
            b1 + l * F_, nullptr, nullptr, mh, nullptr, nullptr, 4096, F_, C_);
        k_gemm<2><<<6 * 32, 256, 0, stream>>>(mh, w2T + (size_t)l * CFE,
            b2 + l * C_, nullptr, nullptr, x, x, nullptr, 4096, C_, F_);
    }
    k_ln<<<1024, 256, 0, stream>>>(x, lnfs, lnfb, h);
    k_gemmh<<<4000, 512, 0, stream>>>(h, whT, out, 4096, V_, C_);
}

// Round 17
// 1036.490 us; speedup vs baseline: 1.0648x; 1.0273x over previous
//
#include <hip/hip_runtime.h>
#include <stdint.h>

// ---- problem constants (fixed by the reference) ----
#define B_ 4
#define T_ 1024
#define C_ 768
#define H_ 12
#define D_ 64
#define F_ 3072
#define V_ 32000
#define L_ 4

typedef unsigned short ushort_t;
typedef __bf16 bf16x8 __attribute__((ext_vector_type(8)));
typedef float f32x4 __attribute__((ext_vector_type(4)));
typedef unsigned short u16x8 __attribute__((ext_vector_type(8)));

__device__ __forceinline__ float b2f(unsigned short u) {
    union { unsigned int i; float f; } x; x.i = ((unsigned int)u) << 16; return x.f;
}
__device__ __forceinline__ unsigned short f2b(float f) {
    union { float f; unsigned int i; } x; x.f = f;
    unsigned int r = x.i + 0x7FFFu + ((x.i >> 16) & 1u);
    return (unsigned short)(r >> 16);
}

// fast exact-GELU: erf via Abramowitz-Stegun 7.1.26 (|eps| <= 1.5e-7)
__device__ __forceinline__ float gelu_f(float u) {
    float z = fabsf(u) * 0.70710678118654752f;
    float t = __builtin_amdgcn_rcpf(1.0f + 0.3275911f * z);
    float poly = t * (0.254829592f + t * (-0.284496736f + t * (1.421413741f +
                 t * (-1.453152027f + t * 1.061405429f))));
    float erfz = 1.0f - poly * __expf(-z * z);
    return u * 0.5f * (1.0f + copysignf(erfz, u));
}

// async global->LDS, 16B per lane; LDS dest = wave-uniform base, HW scatters lane*16B
__device__ __forceinline__ void gload16(const ushort_t* g, ushort_t* l) {
    __builtin_amdgcn_global_load_lds(
        (const __attribute__((address_space(1))) unsigned int*)g,
        (__attribute__((address_space(3))) unsigned int*)l, 16, 0, 0);
}

// ---------------------------------------------------------------------------
// embedding: x (bf16) = tok_emb[idx] + pos_emb
// ---------------------------------------------------------------------------
__global__ __launch_bounds__(256) void k_embed(const int* __restrict__ idx,
        const float* __restrict__ tok, const float* __restrict__ pos,
        ushort_t* __restrict__ x) {
    int i = blockIdx.x * 256 + threadIdx.x;
    int m = i / (C_ / 4);
    int cc = (i % (C_ / 4)) * 4;
    int t = m & (T_ - 1);
    int tokid = idx[m];
    float4 te = *(const float4*)&tok[(size_t)tokid * C_ + cc];
    float4 pe = *(const float4*)&pos[(size_t)t * C_ + cc];
    ushort4 o;
    o.x = f2b(te.x + pe.x); o.y = f2b(te.y + pe.y);
    o.z = f2b(te.z + pe.z); o.w = f2b(te.w + pe.w);
    *(ushort4*)&x[(size_t)m * C_ + cc] = o;
}

// ---------------------------------------------------------------------------
// LayerNorm: bf16 in -> bf16 out.  one ROW per WAVE, 4 rows/block.
// ---------------------------------------------------------------------------
__global__ __launch_bounds__(256) void k_ln(const ushort_t* __restrict__ x,
        const float* __restrict__ s, const float* __restrict__ b,
        ushort_t* __restrict__ out) {
    const int lane = threadIdx.x & 63, wave = threadIdx.x >> 6;
    const int row = blockIdx.x * 4 + wave;
    const ushort_t* xr = x + (size_t)row * C_;
    float vf[3][4];
    float sum = 0.f, sq = 0.f;
#pragma unroll
    for (int j = 0; j < 3; ++j) {
        ushort4 u = *(const ushort4*)&xr[lane * 4 + j * 256];
        vf[j][0] = b2f(u.x); vf[j][1] = b2f(u.y); vf[j][2] = b2f(u.z); vf[j][3] = b2f(u.w);
#pragma unroll
        for (int e = 0; e < 4; ++e) { sum += vf[j][e]; sq += vf[j][e] * vf[j][e]; }
    }
#pragma unroll
    for (int off = 1; off < 64; off <<= 1) {
        sum += __shfl_xor(sum, off);
        sq  += __shfl_xor(sq,  off);
    }
    float mean = sum * (1.f / C_);
    float var  = sq * (1.f / C_) - mean * mean;
    float rstd = rsqrtf(var + 1e-5f);
#pragma unroll
    for (int j = 0; j < 3; ++j) {
        int c = lane * 4 + j * 256;
        float4 sv = *(const float4*)&s[c];
        float4 bv = *(const float4*)&b[c];
        ushort4 o;
        o.x = f2b((vf[j][0] - mean) * rstd * sv.x + bv.x);
        o.y = f2b((vf[j][1] - mean) * rstd * sv.y + bv.y);
        o.z = f2b((vf[j][2] - mean) * rstd * sv.z + bv.z);
        o.w = f2b((vf[j][3] - mean) * rstd * sv.w + bv.w);
        *(ushort4*)&out[(size_t)row * C_ + c] = o;
    }
}

// ---------------------------------------------------------------------------
// batched weight transpose+convert: f32 [R,C] -> bf16 [C,R]
// ---------------------------------------------------------------------------
__global__ void k_tcvt(const float* __restrict__ in, ushort_t* __restrict__ out,
                       int R, int C) {
    __shared__ float tile[32][33];
    const float* src = in + (size_t)blockIdx.z * R * C;
    ushort_t* dst = out + (size_t)blockIdx.z * R * C;
    int r0 = blockIdx.y * 32, c0 = blockIdx.x * 32;
    int tx = threadIdx.x, ty = threadIdx.y;
#pragma unroll
    for (int i = ty; i < 32; i += 8)
        tile[i][tx] = src[(size_t)(r0 + i) * C + c0 + tx];
    __syncthreads();
#pragma unroll
    for (int i = ty; i < 32; i += 8)
        dst[(size_t)(c0 + i) * R + r0 + tx] = f2b(tile[tx][i]);
}

__global__ void k_tcvt16(const float* __restrict__ wq, const float* __restrict__ wk,
                         const float* __restrict__ wv, const float* __restrict__ wp,
                         ushort_t* __restrict__ out) {
    __shared__ float tile[32][33];
    int l = blockIdx.z >> 2, w = blockIdx.z & 3;
    const float* src = (w == 0 ? wq : w == 1 ? wk : w == 2 ? wv : wp) + (size_t)l * C_ * C_;
    ushort_t* dst = out + (size_t)blockIdx.z * C_ * C_;
    int r0 = blockIdx.y * 32, c0 = blockIdx.x * 32;
    int tx = threadIdx.x, ty = threadIdx.y;
#pragma unroll
    for (int i = ty; i < 32; i += 8)
        tile[i][tx] = src[(size_t)(r0 + i) * C_ + c0 + tx];
    __syncthreads();
#pragma unroll
    for (int i = ty; i < 32; i += 8)
        dst[(size_t)(c0 + i) * C_ + r0 + tx] = f2b(tile[tx][i]);
}

// ---------------------------------------------------------------------------
// GEMM 128x128 (mid GEMMs): BK=32, 4 waves, 3-buffer ring, counted vmcnt(4),
// slot-XOR swizzle, supertile order, one barrier per K-step.
// EPI: 1 = +bias GELU wide bf16
//      2 = +bias +resid(bf16 outb2), bf16 wide store to outb (in-place x ok)
//      3 = QKV scatter, wide: q/k -> [B,H,T,D], v -> [B,H,D,T]; all via LDS
// ---------------------------------------------------------------------------
template <int EPI>
__global__ __launch_bounds__(256) void k_gemm(
        const ushort_t* __restrict__ A, const ushort_t* __restrict__ BT,
        const float* __restrict__ bias, const float* __restrict__ resid,
        float* __restrict__ outf, ushort_t* __restrict__ outb,
        ushort_t* __restrict__ outb2, ushort_t* __restrict__ outb3,
        int M, int N, int K) {
    __shared__ __align__(16) ushort_t S[24576];
    const int tid = threadIdx.x;
    const int lane = tid & 63, wave = tid >> 6;
    const int lr = lane & 15, lg = lane >> 4;
    const int wm = (wave >> 1) * 64, wn = (wave & 1) * 64;

    const int bid = blockIdx.x;
    const int m_in = bid & 7;
    const int strip = (bid >> 3) & 3;
    const int ncol = bid >> 5;
    const int m0 = (strip * 8 + m_in) << 7;
    const int n0 = ncol << 7;

    const int sr = wave * 16 + (lane >> 2);
    const int sc = (((lane & 3) ^ ((lane >> 3) & 3)) << 3);

    f32x4 acc[4][4];
#pragma unroll
    for (int i = 0; i < 4; ++i)
#pragma unroll
        for (int j = 0; j < 4; ++j) acc[i][j] = (f32x4){0.f, 0.f, 0.f, 0.f};

    auto stage = [&](int k0, int buf) {
        ushort_t* as = S + buf * 4096;
        ushort_t* bs = S + 12288 + buf * 4096;
        gload16(&A [(size_t)(m0 + sr)      * K + k0 + sc], as + (wave * 16) * 32);
        gload16(&A [(size_t)(m0 + 64 + sr) * K + k0 + sc], as + (64 + wave * 16) * 32);
        gload16(&BT[(size_t)(n0 + sr)      * K + k0 + sc], bs + (wave * 16) * 32);
        gload16(&BT[(size_t)(n0 + 64 + sr) * K + k0 + sc], bs + (64 + wave * 16) * 32);
    };

    const int nt = K >> 5;
    stage(0, 0);
    stage(32, 1);
    int cur = 0, pre = 2;
    const int swzr = (lr >> 1) & 3;
    for (int t = 0; t < nt; ++t) {
        if (t + 1 < nt) asm volatile("s_waitcnt vmcnt(4)" ::: "memory");
        else            asm volatile("s_waitcnt vmcnt(0)" ::: "memory");
        __builtin_amdgcn_sched_barrier(0);
        __builtin_amdgcn_s_barrier();
        const ushort_t* as = S + cur * 4096;
        const ushort_t* bs = S + 12288 + cur * 4096;
        bf16x8 af[4], bfr[4];
#pragma unroll
        for (int i = 0; i < 4; ++i)
            af[i]  = *(const bf16x8*)&as[(wm + i * 16 + lr) * 32 + ((lg ^ swzr) << 3)];
#pragma unroll
        for (int j = 0; j < 4; ++j)
            bfr[j] = *(const bf16x8*)&bs[(wn + j * 16 + lr) * 32 + ((lg ^ swzr) << 3)];
        if (t + 2 < nt) stage((t + 2) << 5, pre);
#pragma unroll
        for (int i = 0; i < 4; ++i)
#pragma unroll
            for (int j = 0; j < 4; ++j)
                acc[i][j] = __builtin_amdgcn_mfma_f32_16x16x32_bf16(af[i], bfr[j], acc[i][j], 0, 0, 0);
        cur = (cur == 2) ? 0 : cur + 1;
        pre = (pre == 2) ? 0 : pre + 1;
    }

    if (EPI == 2) {
        // +bias +bf16 resid (outb2), wide bf16 stores to outb (in-place x ok)
        float* cls = (float*)S;                       // [64][128] f32 = 32KB
#pragma unroll
        for (int h = 0; h < 2; ++h) {
            __syncthreads();
            if ((wm >> 6) == h) {
#pragma unroll
                for (int i = 0; i < 4; ++i)
#pragma unroll
                    for (int j = 0; j < 4; ++j)
#pragma unroll
                        for (int r = 0; r < 4; ++r)
                            cls[(i * 16 + lg * 4 + r) * 128 + wn + j * 16 + lr] = acc[i][j][r];
            }
            __syncthreads();
#pragma unroll
            for (int p = 0; p < 4; ++p) {
                int idx = p * 256 + tid;
                int row = idx >> 4;
                int colc = (idx & 15) * 8;
                f32x4 v0 = *(const f32x4*)&cls[row * 128 + colc];
                f32x4 v1 = *(const f32x4*)&cls[row * 128 + colc + 4];
                size_t gidx = (size_t)(m0 + h * 64 + row) * N + n0 + colc;
                u16x8 rv = *(const u16x8*)&outb2[gidx];
                f32x4 b0 = *(const f32x4*)&bias[n0 + colc];
                f32x4 b1 = *(const f32x4*)&bias[n0 + colc + 4];
                u16x8 o;
#pragma unroll
                for (int e = 0; e < 4; ++e) o[e]     = f2b(v0[e] + b0[e] + b2f(rv[e]));
#pragma unroll
                for (int e = 0; e < 4; ++e) o[4 + e] = f2b(v1[e] + b1[e] + b2f(rv[4 + e]));
                *(u16x8*)&outb[gidx] = o;
            }
        }
        return;
    }

    if (EPI == 1) {
        ushort_t* cls = S;                            // [128][128] bf16 = 32KB
        __syncthreads();
#pragma unroll
        for (int i = 0; i < 4; ++i)
#pragma unroll
            for (int j = 0; j < 4; ++j) {
                float bval = bias[n0 + wn + j * 16 + lr];
#pragma unroll
                for (int r = 0; r < 4; ++r)
                    cls[(wm + i * 16 + lg * 4 + r) * 128 + wn + j * 16 + lr] =
                        f2b(gelu_f(acc[i][j][r] + bval));
            }
        __syncthreads();
#pragma unroll
        for (int p = 0; p < 8; ++p) {
            int row = p * 16 + (tid >> 4);
            int colc = (tid & 15) * 8;
            u16x8 val = *(const u16x8*)&cls[row * 128 + colc];
            *(u16x8*)&outb[(size_t)(m0 + row) * N + n0 + colc] = val;
        }
        return;
    }

    if (EPI == 3) {
        // tile is entirely q (n0<768), k (<1536), or v; spans exactly 2 heads
        const int region = n0 / 768;
        const int c0 = n0 % 768;
        const int bb = m0 >> 10, t0 = m0 & 1023;
        ushort_t* cls = S;                            // [128][136] bf16, pad 8
        if (region < 2) {
            ushort_t* dst = (region == 0) ? outb : outb2;   // [B,H,T,D]
            __syncthreads();
#pragma unroll
            for (int i = 0; i < 4; ++i)
#pragma unroll
                for (int j = 0; j < 4; ++j)
#pragma unroll
                    for (int r = 0; r < 4; ++r)
                        cls[(wm + i * 16 + lg * 4 + r) * 136 + wn + j * 16 + lr] =
                            f2b(acc[i][j][r]);
            __syncthreads();
#pragma unroll
            for (int p = 0; p < 8; ++p) {
                int row = p * 16 + (tid >> 4);
                int colc = (tid & 15) * 8;
                u16x8 val = *(const u16x8*)&cls[row * 136 + colc];
                int hh = (c0 + colc) >> 6, d = (c0 + colc) & 63;
                *(u16x8*)&dst[((((size_t)bb * H_ + hh) << 10) + t0 + row) * D_ + d] = val;
            }
        } else {
            // v: [B,H,D,T]; write tile transposed into LDS, t-contiguous stores
            __syncthreads();
#pragma unroll
            for (int i = 0; i < 4; ++i)
#pragma unroll
                for (int j = 0; j < 4; ++j)
#pragma unroll
                    for (int r = 0; r < 4; ++r)
                        cls[(wn + j * 16 + lr) * 136 + wm + i * 16 + lg * 4 + r] =
                            f2b(acc[i][j][r]);
            __syncthreads();
#pragma unroll
            for (int p = 0; p < 8; ++p) {
                int col = p * 16 + (tid >> 4);        // d-col within tile
                int rowc = (tid & 15) * 8;            // t chunk
                u16x8 val = *(const u16x8*)&cls[col * 136 + rowc];
                int hh = (c0 + col) >> 6, d = (c0 + col) & 63;
                *(u16x8*)&outb3[(((size_t)bb * H_ + hh) * D_ + d) * T_ + t0 + rowc] = val;
            }
        }
        return;
    }
}

// ---------------------------------------------------------------------------
// k_gemmh (head): 128x256 tile, 8 waves (2x4), BK=32, 3-ring (72KB LDS)
// -> 2 blocks/CU.  3 gload16/wave/K-step, counted vmcnt(3), one barrier per
// K-step, slot-XOR swizzle, supertile order (B read once).
// Wide NT f32 epilogue via LDS [64][260].
// ---------------------------------------------------------------------------
__global__ __launch_bounds__(512, 4) void k_gemmh(
        const ushort_t* __restrict__ A, const ushort_t* __restrict__ BT,
        float* __restrict__ outf, int M, int N, int K) {
    __shared__ __align__(16) ushort_t S[36864];   // 72KB: A-ring 3x8KB | B-ring 3x16KB
    const int tid = threadIdx.x;
    const int lane = tid & 63, wave = tid >> 6;
    const int lr = lane & 15, lg = lane >> 4;
    const int wm = (wave >> 2) * 64, wn = (wave & 3) * 64;

    const int bid = blockIdx.x;
    const int m_in = bid & 7;
    const int strip = (bid >> 3) & 3;
    const int ncol = bid >> 5;
    const int m0 = (strip * 8 + m_in) << 7;
    const int n0 = ncol << 8;

    const int srr = lane >> 2;                    // row within 16-row chunk
    const int sc = (((lane & 3) ^ ((lane >> 3) & 3)) << 3);

    f32x4 acc[4][4];
#pragma unroll
    for (int i = 0; i < 4; ++i)
#pragma unroll
        for (int j = 0; j < 4; ++j) acc[i][j] = (f32x4){0.f, 0.f, 0.f, 0.f};

    auto stage = [&](int k0, int buf) {
        ushort_t* as = S + buf * 4096;
        ushort_t* bs = S + 12288 + buf * 8192;
        gload16(&A [(size_t)(m0 + wave * 16 + srr) * K + k0 + sc], as + (wave * 16) * 32);
        gload16(&BT[(size_t)(n0 + wave * 32 + srr)      * K + k0 + sc], bs + (wave * 32) * 32);
        gload16(&BT[(size_t)(n0 + wave * 32 + 16 + srr) * K + k0 + sc], bs + (wave * 32 + 16) * 32);
    };

    const int nt = K >> 5;                        // 24 for K=768
    stage(0, 0);
    stage(32, 1);
    int cur = 0, pre = 2;
    const int swzr = (lr >> 1) & 3;
    for (int t = 0; t < nt; ++t) {
        if (t + 1 < nt) asm volatile("s_waitcnt vmcnt(3)" ::: "memory");
        else            asm volatile("s_waitcnt vmcnt(0)" ::: "memory");
        __builtin_amdgcn_sched_barrier(0);
        __builtin_amdgcn_s_barrier();
        const ushort_t* as = S + cur * 4096;
        const ushort_t* bs = S + 12288 + cur * 8192;
        bf16x8 af[4], bfr[4];
#pragma unroll
        for (int i = 0; i < 4; ++i)
            af[i]  = *(const bf16x8*)&as[(wm + i * 16 + lr) * 32 + ((lg ^ swzr) << 3)];
#pragma unroll
        for (int j = 0; j < 4; ++j)
            bfr[j] = *(const bf16x8*)&bs[(wn + j * 16 + lr) * 32 + ((lg ^ swzr) << 3)];
        if (t + 2 < nt) stage((t + 2) << 5, pre);
#pragma unroll
        for (int i = 0; i < 4; ++i)
#pragma unroll
            for (int j = 0; j < 4; ++j)
                acc[i][j] = __builtin_amdgcn_mfma_f32_16x16x32_bf16(af[i], bfr[j], acc[i][j], 0, 0, 0);
        cur = (cur == 2) ? 0 : cur + 1;
        pre = (pre == 2) ? 0 : pre + 1;
    }

    // wide NT f32 epilogue: 2 passes of 64 rows x 256 cols, LDS [64][260] f32
    float* cls = (float*)S;
#pragma unroll
    for (int h = 0; h < 2; ++h) {
        __syncthreads();
        if ((wm >> 6) == h) {
#pragma unroll
            for (int i = 0; i < 4; ++i)
#pragma unroll
                for (int j = 0; j < 4; ++j)
#pragma unroll
                    for (int r = 0; r < 4; ++r)
                        cls[(i * 16 + lg * 4 + r) * 260 + wn + j * 16 + lr] = acc[i][j][r];
        }
        __syncthreads();
#pragma unroll
        for (int p = 0; p < 8; ++p) {
            int idx = p * 512 + tid;
            int row = idx >> 6;
            int colc = (idx & 63) * 4;
            f32x4 val = *(const f32x4*)&cls[row * 260 + colc];
            __builtin_nontemporal_store(val,
                (f32x4*)&outf[(size_t)(m0 + h * 64 + row) * N + n0 + colc]);
        }
    }
}

// ---------------------------------------------------------------------------
// flash attention, swapped-QK^T softmax (S^T = mfma(K,Q): scalar ls, 2-shfl
// reduce), KVBLK=128, no online max, P packed via v_cvt_pk_bf16_f32.
// Output staged through LDS -> wide u16x8 stores (128B runs along d).
// ---------------------------------------------------------------------------
__global__ __launch_bounds__(256) void k_attn(const ushort_t* __restrict__ q,
        const ushort_t* __restrict__ k, const ushort_t* __restrict__ vT,
        ushort_t* __restrict__ yc) {
    __shared__ __align__(16) ushort_t P[4][16 * 136];
    const int lane = threadIdx.x & 63, wave = threadIdx.x >> 6;
    const int lr = lane & 15, lg = lane >> 4;
    const int bh = blockIdx.x;
    const int bb = bh / H_, hh = bh % H_;
    const int qrow0 = (gridDim.y - 1 - blockIdx.y) * 64 + wave * 16;
    const ushort_t* qb = q + (size_t)bh * T_ * D_;
    const ushort_t* kb = k + (size_t)bh * T_ * D_;
    const ushort_t* vb = vT + (size_t)bh * D_ * T_;

    bf16x8 aq0 = *(const bf16x8*)&qb[(qrow0 + lr) * D_ + lg * 8];
    bf16x8 aq1 = *(const bf16x8*)&qb[(qrow0 + lr) * D_ + 32 + lg * 8];

    f32x4 accY[4];
    float ls = 0.f;
#pragma unroll
    for (int d = 0; d < 4; ++d) accY[d] = (f32x4){0.f, 0.f, 0.f, 0.f};

    ushort_t* pw = &P[wave][0];
    const int kv_end = qrow0 + 16;
    for (int kv0 = 0; kv0 < kv_end; kv0 += 128) {
        const bool full = (kv0 + 127 <= qrow0);       // wave-uniform
        float p[8][4];
        float ps = 0.f;
#pragma unroll
        for (int j = 0; j < 8; ++j) {
            f32x4 s = (f32x4){0.f, 0.f, 0.f, 0.f};
            bf16x8 bk0 = *(const bf16x8*)&kb[(kv0 + j * 16 + lr) * D_ + lg * 8];
            bf16x8 bk1 = *(const bf16x8*)&kb[(kv0 + j * 16 + lr) * D_ + 32 + lg * 8];
            __builtin_amdgcn_s_setprio(1);
            s = __builtin_amdgcn_mfma_f32_16x16x32_bf16(bk0, aq0, s, 0, 0, 0);
            s = __builtin_amdgcn_mfma_f32_16x16x32_bf16(bk1, aq1, s, 0, 0, 0);
            __builtin_amdgcn_s_setprio(0);
            // lane holds S^T[k = kv0+j*16+lg*4+r][q = qrow0+lr]
            if (full) {
#pragma unroll
                for (int r = 0; r < 4; ++r) { p[j][r] = __expf(s[r] * 0.125f); ps += p[j][r]; }
            } else {
                int kcb = kv0 + j * 16 + lg * 4;
#pragma unroll
                for (int r = 0; r < 4; ++r) {
                    p[j][r] = (kcb + r <= qrow0 + lr) ? __expf(s[r] * 0.125f) : 0.f;
                    ps += p[j][r];
                }
            }
        }
        ps += __shfl_xor(ps, 16);
        ps += __shfl_xor(ps, 32);
        ls += ps;

        // previous iteration's pa reads must be complete before overwrite
        asm volatile("s_waitcnt lgkmcnt(0)" ::: "memory");
        __builtin_amdgcn_sched_barrier(0);
#pragma unroll
        for (int j = 0; j < 8; ++j) {
            unsigned int w0, w1;
            asm("v_cvt_pk_bf16_f32 %0, %1, %2" : "=v"(w0) : "v"(p[j][0]), "v"(p[j][1]));
            asm("v_cvt_pk_bf16_f32 %0, %1, %2" : "=v"(w1) : "v"(p[j][2]), "v"(p[j][3]));
            uint2 w; w.x = w0; w.y = w1;
            *(uint2*)&pw[lr * 136 + j * 16 + lg * 4] = w;
        }
        asm volatile("s_waitcnt lgkmcnt(0)" ::: "memory");
        __builtin_amdgcn_sched_barrier(0);
        bf16x8 pa[4];
#pragma unroll
        for (int ks = 0; ks < 4; ++ks)
            pa[ks] = *(const bf16x8*)&pw[lr * 136 + ks * 32 + lg * 8];
#pragma unroll
        for (int d = 0; d < 4; ++d) {
            __builtin_amdgcn_s_setprio(1);
#pragma unroll
            for (int ks = 0; ks < 4; ++ks) {
                bf16x8 bv = *(const bf16x8*)&vb[(d * 16 + lr) * T_ + kv0 + ks * 32 + lg * 8];
                accY[d] = __builtin_amdgcn_mfma_f32_16x16x32_bf16(pa[ks], bv, accY[d], 0, 0, 0);
            }
            __builtin_amdgcn_s_setprio(0);
        }
    }
    float inv[4];
#pragma unroll
    for (int r = 0; r < 4; ++r) inv[r] = 1.0f / __shfl(ls, lg * 4 + r);

    // stage output tile (16 x 64) in LDS, then wide 128B stores along d
    asm volatile("s_waitcnt lgkmcnt(0)" ::: "memory");
    __builtin_amdgcn_sched_barrier(0);
#pragma unroll
    for (int d = 0; d < 4; ++d)
#pragma unroll
        for (int r = 0; r < 4; ++r)
            pw[(lg * 4 + r) * 72 + d * 16 + lr] = f2b(accY[d][r] * inv[r]);
    asm volatile("s_waitcnt lgkmcnt(0)" ::: "memory");
    __builtin_amdgcn_sched_barrier(0);
#pragma unroll
    for (int p = 0; p < 2; ++p) {
        int row = p * 8 + (lane >> 3);
        int colc = (lane & 7) * 8;
        u16x8 val = *(const u16x8*)&pw[row * 72 + colc];
        *(u16x8*)&yc[((size_t)bb * T_ + qrow0 + row) * C_ + hh * D_ + colc] = val;
    }
}

// ---------------------------------------------------------------------------
extern "C" void kernel_launch(void* const* d_in, const int* in_sizes, int n_in,
                              void* d_out, int out_size, void* d_ws, size_t ws_size,
                              hipStream_t stream) {
    (void)in_sizes; (void)n_in; (void)out_size; (void)ws_size;
    const int*   idx  = (const int*)d_in[0];
    const float* tok  = (const float*)d_in[1];
    const float* pos  = (const float*)d_in[2];
    const float* Wq   = (const float*)d_in[3];
    const float* Wk   = (const float*)d_in[4];
    const float* Wv   = (const float*)d_in[5];
    const float* Wp   = (const float*)d_in[6];
    const float* bp   = (const float*)d_in[7];
    const float* ln1s = (const float*)d_in[8];
    const float* ln1b = (const float*)d_in[9];
    const float* ln2s = (const float*)d_in[10];
    const float* ln2b = (const float*)d_in[11];
    const float* W1   = (const float*)d_in[12];
    const float* b1   = (const float*)d_in[13];
    const float* W2   = (const float*)d_in[14];
    const float* b2   = (const float*)d_in[15];
    const float* lnfs = (const float*)d_in[16];
    const float* lnfb = (const float*)d_in[17];
    const float* Wh   = (const float*)d_in[18];
    float* out = (float*)d_out;

    char* ws = (char*)d_ws;
    size_t off = 0;
    auto alloc = [&](size_t bytes) { void* p = ws + off; off += (bytes + 255) & ~(size_t)255; return p; };

    const size_t CCE = (size_t)C_ * C_;
    const size_t CFE = (size_t)C_ * F_;
    ushort_t* wCC  = (ushort_t*)alloc(16 * CCE * 2);
    ushort_t* w1T  = (ushort_t*)alloc((size_t)L_ * CFE * 2);
    ushort_t* w2T  = (ushort_t*)alloc((size_t)L_ * CFE * 2);
    ushort_t* whT  = (ushort_t*)alloc((size_t)C_ * V_ * 2);
    ushort_t* x    = (ushort_t*)alloc((size_t)B_ * T_ * C_ * 2);   // bf16 residual stream
    ushort_t* h    = (ushort_t*)alloc((size_t)B_ * T_ * C_ * 2);
    ushort_t* qb_  = (ushort_t*)alloc((size_t)B_ * T_ * C_ * 2);
    ushort_t* kb_  = (ushort_t*)alloc((size_t)B_ * T_ * C_ * 2);
    ushort_t* vTb  = (ushort_t*)alloc((size_t)B_ * T_ * C_ * 2);
    ushort_t* yc   = (ushort_t*)alloc((size_t)B_ * T_ * C_ * 2);
    ushort_t* mh   = (ushort_t*)alloc((size_t)B_ * T_ * F_ * 2);

    dim3 tb(32, 8);
    k_tcvt16<<<dim3(24, 24, 16), tb, 0, stream>>>(Wq, Wk, Wv, Wp, wCC);
    k_tcvt<<<dim3(96, 24, 4), tb, 0, stream>>>(W1, w1T, C_, F_);
    k_tcvt<<<dim3(24, 96, 4), tb, 0, stream>>>(W2, w2T, F_, C_);
    k_tcvt<<<dim3(1000, 24, 1), tb, 0, stream>>>(Wh, whT, C_, V_);

    k_embed<<<3072, 256, 0, stream>>>(idx, tok, pos, x);

    for (int l = 0; l < L_; ++l) {
        k_ln<<<1024, 256, 0, stream>>>(x, ln1s + l * C_, ln1b + l * C_, h);
        k_gemm<3><<<18 * 32, 256, 0, stream>>>(h, wCC + (size_t)(l * 4) * CCE,
            nullptr, nullptr, nullptr, qb_, kb_, vTb, 4096, 3 * C_, C_);
        k_attn<<<dim3(48, 16), 256, 0, stream>>>(qb_, kb_, vTb, yc);
        k_gemm<2><<<6 * 32, 256, 0, stream>>>(yc, wCC + (size_t)(l * 4 + 3) * CCE,
            bp + l * C_, nullptr, nullptr, x, x, nullptr, 4096, C_, C_);
        k_ln<<<1024, 256, 0, stream>>>(x, ln2s + l * C_, ln2b + l * C_, h);
        k_gemm<1><<<24 * 32, 256, 0, stream>>>(h, w1T + (size_t)l * CFE,
            b1 + l * F_, nullptr, nullptr, mh, nullptr, nullptr, 4096, F_, C_);
        k_gemm<2><<<6 * 32, 256, 0, stream>>>(mh, w2T + (size_t)l * CFE,
            b2 + l * C_, nullptr, nullptr, x, x, nullptr, 4096, C_, F_);
    }
    k_ln<<<1024, 256, 0, stream>>>(x, lnfs, lnfb, h);
    k_gemmh<<<4000, 512, 0, stream>>>(h, whT, out, 4096, V_, C_);
}

// Round 18
// 1012.392 us; speedup vs baseline: 1.0902x; 1.0238x over previous
//
#include <hip/hip_runtime.h>
#include <stdint.h>

// ---- problem constants (fixed by the reference) ----
#define B_ 4
#define T_ 1024
#define C_ 768
#define H_ 12
#define D_ 64
#define F_ 3072
#define V_ 32000
#define L_ 4

typedef unsigned short ushort_t;
typedef __bf16 bf16x8 __attribute__((ext_vector_type(8)));
typedef float f32x4 __attribute__((ext_vector_type(4)));
typedef unsigned short u16x8 __attribute__((ext_vector_type(8)));

__device__ __forceinline__ float b2f(unsigned short u) {
    union { unsigned int i; float f; } x; x.i = ((unsigned int)u) << 16; return x.f;
}
__device__ __forceinline__ unsigned short f2b(float f) {
    union { float f; unsigned int i; } x; x.f = f;
    unsigned int r = x.i + 0x7FFFu + ((x.i >> 16) & 1u);
    return (unsigned short)(r >> 16);
}

// fast exact-GELU: erf via Abramowitz-Stegun 7.1.26 (|eps| <= 1.5e-7)
__device__ __forceinline__ float gelu_f(float u) {
    float z = fabsf(u) * 0.70710678118654752f;
    float t = __builtin_amdgcn_rcpf(1.0f + 0.3275911f * z);
    float poly = t * (0.254829592f + t * (-0.284496736f + t * (1.421413741f +
                 t * (-1.453152027f + t * 1.061405429f))));
    float erfz = 1.0f - poly * __expf(-z * z);
    return u * 0.5f * (1.0f + copysignf(erfz, u));
}

// async global->LDS, 16B per lane; LDS dest = wave-uniform base, HW scatters lane*16B
__device__ __forceinline__ void gload16(const ushort_t* g, ushort_t* l) {
    __builtin_amdgcn_global_load_lds(
        (const __attribute__((address_space(1))) unsigned int*)g,
        (__attribute__((address_space(3))) unsigned int*)l, 16, 0, 0);
}

// ---------------------------------------------------------------------------
// embedding: x (bf16) = tok_emb[idx] + pos_emb
// ---------------------------------------------------------------------------
__global__ __launch_bounds__(256) void k_embed(const int* __restrict__ idx,
        const float* __restrict__ tok, const float* __restrict__ pos,
        ushort_t* __restrict__ x) {
    int i = blockIdx.x * 256 + threadIdx.x;
    int m = i / (C_ / 4);
    int cc = (i % (C_ / 4)) * 4;
    int t = m & (T_ - 1);
    int tokid = idx[m];
    float4 te = *(const float4*)&tok[(size_t)tokid * C_ + cc];
    float4 pe = *(const float4*)&pos[(size_t)t * C_ + cc];
    ushort4 o;
    o.x = f2b(te.x + pe.x); o.y = f2b(te.y + pe.y);
    o.z = f2b(te.z + pe.z); o.w = f2b(te.w + pe.w);
    *(ushort4*)&x[(size_t)m * C_ + cc] = o;
}

// ---------------------------------------------------------------------------
// LayerNorm: bf16 in -> bf16 out.  one ROW per WAVE, 4 rows/block.
// ---------------------------------------------------------------------------
__global__ __launch_bounds__(256) void k_ln(const ushort_t* __restrict__ x,
        const float* __restrict__ s, const float* __restrict__ b,
        ushort_t* __restrict__ out) {
    const int lane = threadIdx.x & 63, wave = threadIdx.x >> 6;
    const int row = blockIdx.x * 4 + wave;
    const ushort_t* xr = x + (size_t)row * C_;
    float vf[3][4];
    float sum = 0.f, sq = 0.f;
#pragma unroll
    for (int j = 0; j < 3; ++j) {
        ushort4 u = *(const ushort4*)&xr[lane * 4 + j * 256];
        vf[j][0] = b2f(u.x); vf[j][1] = b2f(u.y); vf[j][2] = b2f(u.z); vf[j][3] = b2f(u.w);
#pragma unroll
        for (int e = 0; e < 4; ++e) { sum += vf[j][e]; sq += vf[j][e] * vf[j][e]; }
    }
#pragma unroll
    for (int off = 1; off < 64; off <<= 1) {
        sum += __shfl_xor(sum, off);
        sq  += __shfl_xor(sq,  off);
    }
    float mean = sum * (1.f / C_);
    float var  = sq * (1.f / C_) - mean * mean;
    float rstd = rsqrtf(var + 1e-5f);
#pragma unroll
    for (int j = 0; j < 3; ++j) {
        int c = lane * 4 + j * 256;
        float4 sv = *(const float4*)&s[c];
        float4 bv = *(const float4*)&b[c];
        ushort4 o;
        o.x = f2b((vf[j][0] - mean) * rstd * sv.x + bv.x);
        o.y = f2b((vf[j][1] - mean) * rstd * sv.y + bv.y);
        o.z = f2b((vf[j][2] - mean) * rstd * sv.z + bv.z);
        o.w = f2b((vf[j][3] - mean) * rstd * sv.w + bv.w);
        *(ushort4*)&out[(size_t)row * C_ + c] = o;
    }
}

// ---------------------------------------------------------------------------
// batched weight transpose+convert: f32 [R,C] -> bf16 [C,R]
// ---------------------------------------------------------------------------
__global__ void k_tcvt(const float* __restrict__ in, ushort_t* __restrict__ out,
                       int R, int C) {
    __shared__ float tile[32][33];
    const float* src = in + (size_t)blockIdx.z * R * C;
    ushort_t* dst = out + (size_t)blockIdx.z * R * C;
    int r0 = blockIdx.y * 32, c0 = blockIdx.x * 32;
    int tx = threadIdx.x, ty = threadIdx.y;
#pragma unroll
    for (int i = ty; i < 32; i += 8)
        tile[i][tx] = src[(size_t)(r0 + i) * C + c0 + tx];
    __syncthreads();
#pragma unroll
    for (int i = ty; i < 32; i += 8)
        dst[(size_t)(c0 + i) * R + r0 + tx] = f2b(tile[tx][i]);
}

__global__ void k_tcvt16(const float* __restrict__ wq, const float* __restrict__ wk,
                         const float* __restrict__ wv, const float* __restrict__ wp,
                         ushort_t* __restrict__ out) {
    __shared__ float tile[32][33];
    int l = blockIdx.z >> 2, w = blockIdx.z & 3;
    const float* src = (w == 0 ? wq : w == 1 ? wk : w == 2 ? wv : wp) + (size_t)l * C_ * C_;
    ushort_t* dst = out + (size_t)blockIdx.z * C_ * C_;
    int r0 = blockIdx.y * 32, c0 = blockIdx.x * 32;
    int tx = threadIdx.x, ty = threadIdx.y;
#pragma unroll
    for (int i = ty; i < 32; i += 8)
        tile[i][tx] = src[(size_t)(r0 + i) * C_ + c0 + tx];
    __syncthreads();
#pragma unroll
    for (int i = ty; i < 32; i += 8)
        dst[(size_t)(c0 + i) * C_ + r0 + tx] = f2b(tile[tx][i]);
}

// ---------------------------------------------------------------------------
// GEMM 128x128 (mid GEMMs): BK=32, 4 waves, 3-buffer ring, counted vmcnt(4),
// slot-XOR swizzle, supertile order, one barrier per K-step.
// EPI: 1 = +bias GELU wide bf16
//      2 = +bias +resid(bf16 outb2), bf16 wide store to outb (in-place x ok)
//      3 = QKV scatter, wide: q/k -> [B,H,T,D], v -> [B,H,D,T]; all via LDS
// ---------------------------------------------------------------------------
template <int EPI>
__global__ __launch_bounds__(256) void k_gemm(
        const ushort_t* __restrict__ A, const ushort_t* __restrict__ BT,
        const float* __restrict__ bias, const float* __restrict__ resid,
        float* __restrict__ outf, ushort_t* __restrict__ outb,
        ushort_t* __restrict__ outb2, ushort_t* __restrict__ outb3,
        int M, int N, int K) {
    __shared__ __align__(16) ushort_t S[24576];
    const int tid = threadIdx.x;
    const int lane = tid & 63, wave = tid >> 6;
    const int lr = lane & 15, lg = lane >> 4;
    const int wm = (wave >> 1) * 64, wn = (wave & 1) * 64;

    const int bid = blockIdx.x;
    const int m_in = bid & 7;
    const int strip = (bid >> 3) & 3;
    const int ncol = bid >> 5;
    const int m0 = (strip * 8 + m_in) << 7;
    const int n0 = ncol << 7;

    const int sr = wave * 16 + (lane >> 2);
    const int sc = (((lane & 3) ^ ((lane >> 3) & 3)) << 3);

    f32x4 acc[4][4];
#pragma unroll
    for (int i = 0; i < 4; ++i)
#pragma unroll
        for (int j = 0; j < 4; ++j) acc[i][j] = (f32x4){0.f, 0.f, 0.f, 0.f};

    auto stage = [&](int k0, int buf) {
        ushort_t* as = S + buf * 4096;
        ushort_t* bs = S + 12288 + buf * 4096;
        gload16(&A [(size_t)(m0 + sr)      * K + k0 + sc], as + (wave * 16) * 32);
        gload16(&A [(size_t)(m0 + 64 + sr) * K + k0 + sc], as + (64 + wave * 16) * 32);
        gload16(&BT[(size_t)(n0 + sr)      * K + k0 + sc], bs + (wave * 16) * 32);
        gload16(&BT[(size_t)(n0 + 64 + sr) * K + k0 + sc], bs + (64 + wave * 16) * 32);
    };

    const int nt = K >> 5;
    stage(0, 0);
    stage(32, 1);
    int cur = 0, pre = 2;
    const int swzr = (lr >> 1) & 3;
    for (int t = 0; t < nt; ++t) {
        if (t + 1 < nt) asm volatile("s_waitcnt vmcnt(4)" ::: "memory");
        else            asm volatile("s_waitcnt vmcnt(0)" ::: "memory");
        __builtin_amdgcn_sched_barrier(0);
        __builtin_amdgcn_s_barrier();
        const ushort_t* as = S + cur * 4096;
        const ushort_t* bs = S + 12288 + cur * 4096;
        bf16x8 af[4], bfr[4];
#pragma unroll
        for (int i = 0; i < 4; ++i)
            af[i]  = *(const bf16x8*)&as[(wm + i * 16 + lr) * 32 + ((lg ^ swzr) << 3)];
#pragma unroll
        for (int j = 0; j < 4; ++j)
            bfr[j] = *(const bf16x8*)&bs[(wn + j * 16 + lr) * 32 + ((lg ^ swzr) << 3)];
        if (t + 2 < nt) stage((t + 2) << 5, pre);
#pragma unroll
        for (int i = 0; i < 4; ++i)
#pragma unroll
            for (int j = 0; j < 4; ++j)
                acc[i][j] = __builtin_amdgcn_mfma_f32_16x16x32_bf16(af[i], bfr[j], acc[i][j], 0, 0, 0);
        cur = (cur == 2) ? 0 : cur + 1;
        pre = (pre == 2) ? 0 : pre + 1;
    }

    if (EPI == 2) {
        // +bias +bf16 resid (outb2), wide bf16 stores to outb (in-place x ok)
        float* cls = (float*)S;                       // [64][128] f32 = 32KB
#pragma unroll
        for (int h = 0; h < 2; ++h) {
            __syncthreads();
            if ((wm >> 6) == h) {
#pragma unroll
                for (int i = 0; i < 4; ++i)
#pragma unroll
                    for (int j = 0; j < 4; ++j)
#pragma unroll
                        for (int r = 0; r < 4; ++r)
                            cls[(i * 16 + lg * 4 + r) * 128 + wn + j * 16 + lr] = acc[i][j][r];
            }
            __syncthreads();
#pragma unroll
            for (int p = 0; p < 4; ++p) {
                int idx = p * 256 + tid;
                int row = idx >> 4;
                int colc = (idx & 15) * 8;
                f32x4 v0 = *(const f32x4*)&cls[row * 128 + colc];
                f32x4 v1 = *(const f32x4*)&cls[row * 128 + colc + 4];
                size_t gidx = (size_t)(m0 + h * 64 + row) * N + n0 + colc;
                u16x8 rv = *(const u16x8*)&outb2[gidx];
                f32x4 b0 = *(const f32x4*)&bias[n0 + colc];
                f32x4 b1 = *(const f32x4*)&bias[n0 + colc + 4];
                u16x8 o;
#pragma unroll
                for (int e = 0; e < 4; ++e) o[e]     = f2b(v0[e] + b0[e] + b2f(rv[e]));
#pragma unroll
                for (int e = 0; e < 4; ++e) o[4 + e] = f2b(v1[e] + b1[e] + b2f(rv[4 + e]));
                *(u16x8*)&outb[gidx] = o;
            }
        }
        return;
    }

    if (EPI == 1) {
        ushort_t* cls = S;                            // [128][128] bf16 = 32KB
        __syncthreads();
#pragma unroll
        for (int i = 0; i < 4; ++i)
#pragma unroll
            for (int j = 0; j < 4; ++j) {
                float bval = bias[n0 + wn + j * 16 + lr];
#pragma unroll
                for (int r = 0; r < 4; ++r)
                    cls[(wm + i * 16 + lg * 4 + r) * 128 + wn + j * 16 + lr] =
                        f2b(gelu_f(acc[i][j][r] + bval));
            }
        __syncthreads();
#pragma unroll
        for (int p = 0; p < 8; ++p) {
            int row = p * 16 + (tid >> 4);
            int colc = (tid & 15) * 8;
            u16x8 val = *(const u16x8*)&cls[row * 128 + colc];
            *(u16x8*)&outb[(size_t)(m0 + row) * N + n0 + colc] = val;
        }
        return;
    }

    if (EPI == 3) {
        // tile is entirely q (n0<768), k (<1536), or v; spans exactly 2 heads
        const int region = n0 / 768;
        const int c0 = n0 % 768;
        const int bb = m0 >> 10, t0 = m0 & 1023;
        ushort_t* cls = S;                            // [128][136] bf16, pad 8
        if (region < 2) {
            ushort_t* dst = (region == 0) ? outb : outb2;   // [B,H,T,D]
            __syncthreads();
#pragma unroll
            for (int i = 0; i < 4; ++i)
#pragma unroll
                for (int j = 0; j < 4; ++j)
#pragma unroll
                    for (int r = 0; r < 4; ++r)
                        cls[(wm + i * 16 + lg * 4 + r) * 136 + wn + j * 16 + lr] =
                            f2b(acc[i][j][r]);
            __syncthreads();
#pragma unroll
            for (int p = 0; p < 8; ++p) {
                int row = p * 16 + (tid >> 4);
                int colc = (tid & 15) * 8;
                u16x8 val = *(const u16x8*)&cls[row * 136 + colc];
                int hh = (c0 + colc) >> 6, d = (c0 + colc) & 63;
                *(u16x8*)&dst[((((size_t)bb * H_ + hh) << 10) + t0 + row) * D_ + d] = val;
            }
        } else {
            // v: [B,H,D,T]; write tile transposed into LDS, t-contiguous stores
            __syncthreads();
#pragma unroll
            for (int i = 0; i < 4; ++i)
#pragma unroll
                for (int j = 0; j < 4; ++j)
#pragma unroll
                    for (int r = 0; r < 4; ++r)
                        cls[(wn + j * 16 + lr) * 136 + wm + i * 16 + lg * 4 + r] =
                            f2b(acc[i][j][r]);
            __syncthreads();
#pragma unroll
            for (int p = 0; p < 8; ++p) {
                int col = p * 16 + (tid >> 4);        // d-col within tile
                int rowc = (tid & 15) * 8;            // t chunk
                u16x8 val = *(const u16x8*)&cls[col * 136 + rowc];
                int hh = (c0 + col) >> 6, d = (c0 + col) & 63;
                *(u16x8*)&outb3[(((size_t)bb * H_ + hh) * D_ + d) * T_ + t0 + rowc] = val;
            }
        }
        return;
    }
}

// ---------------------------------------------------------------------------
// k_gemmh (head): 128x256 tile, 8 waves (2x4), BK=32, 3-ring (72KB LDS)
// -> 2 blocks/CU.  3 gload16/wave/K-step, counted vmcnt(3), one barrier per
// K-step, slot-XOR swizzle, supertile order (B read once).
// Wide NT f32 epilogue via LDS [64][260].
// ---------------------------------------------------------------------------
__global__ __launch_bounds__(512, 4) void k_gemmh(
        const ushort_t* __restrict__ A, const ushort_t* __restrict__ BT,
        float* __restrict__ outf, int M, int N, int K) {
    __shared__ __align__(16) ushort_t S[36864];   // 72KB: A-ring 3x8KB | B-ring 3x16KB
    const int tid = threadIdx.x;
    const int lane = tid & 63, wave = tid >> 6;
    const int lr = lane & 15, lg = lane >> 4;
    const int wm = (wave >> 2) * 64, wn = (wave & 3) * 64;

    const int bid = blockIdx.x;
    const int m_in = bid & 7;
    const int strip = (bid >> 3) & 3;
    const int ncol = bid >> 5;
    const int m0 = (strip * 8 + m_in) << 7;
    const int n0 = ncol << 8;

    const int srr = lane >> 2;                    // row within 16-row chunk
    const int sc = (((lane & 3) ^ ((lane >> 3) & 3)) << 3);

    f32x4 acc[4][4];
#pragma unroll
    for (int i = 0; i < 4; ++i)
#pragma unroll
        for (int j = 0; j < 4; ++j) acc[i][j] = (f32x4){0.f, 0.f, 0.f, 0.f};

    auto stage = [&](int k0, int buf) {
        ushort_t* as = S + buf * 4096;
        ushort_t* bs = S + 12288 + buf * 8192;
        gload16(&A [(size_t)(m0 + wave * 16 + srr) * K + k0 + sc], as + (wave * 16) * 32);
        gload16(&BT[(size_t)(n0 + wave * 32 + srr)      * K + k0 + sc], bs + (wave * 32) * 32);
        gload16(&BT[(size_t)(n0 + wave * 32 + 16 + srr) * K + k0 + sc], bs + (wave * 32 + 16) * 32);
    };

    const int nt = K >> 5;                        // 24 for K=768
    stage(0, 0);
    stage(32, 1);
    int cur = 0, pre = 2;
    const int swzr = (lr >> 1) & 3;
    for (int t = 0; t < nt; ++t) {
        if (t + 1 < nt) asm volatile("s_waitcnt vmcnt(3)" ::: "memory");
        else            asm volatile("s_waitcnt vmcnt(0)" ::: "memory");
        __builtin_amdgcn_sched_barrier(0);
        __builtin_amdgcn_s_barrier();
        const ushort_t* as = S + cur * 4096;
        const ushort_t* bs = S + 12288 + cur * 8192;
        bf16x8 af[4], bfr[4];
#pragma unroll
        for (int i = 0; i < 4; ++i)
            af[i]  = *(const bf16x8*)&as[(wm + i * 16 + lr) * 32 + ((lg ^ swzr) << 3)];
#pragma unroll
        for (int j = 0; j < 4; ++j)
            bfr[j] = *(const bf16x8*)&bs[(wn + j * 16 + lr) * 32 + ((lg ^ swzr) << 3)];
        if (t + 2 < nt) stage((t + 2) << 5, pre);
#pragma unroll
        for (int i = 0; i < 4; ++i)
#pragma unroll
            for (int j = 0; j < 4; ++j)
                acc[i][j] = __builtin_amdgcn_mfma_f32_16x16x32_bf16(af[i], bfr[j], acc[i][j], 0, 0, 0);
        cur = (cur == 2) ? 0 : cur + 1;
        pre = (pre == 2) ? 0 : pre + 1;
    }

    // wide NT f32 epilogue: 2 passes of 64 rows x 256 cols, LDS [64][260] f32
    float* cls = (float*)S;
#pragma unroll
    for (int h = 0; h < 2; ++h) {
        __syncthreads();
        if ((wm >> 6) == h) {
#pragma unroll
            for (int i = 0; i < 4; ++i)
#pragma unroll
                for (int j = 0; j < 4; ++j)
#pragma unroll
                    for (int r = 0; r < 4; ++r)
                        cls[(i * 16 + lg * 4 + r) * 260 + wn + j * 16 + lr] = acc[i][j][r];
        }
        __syncthreads();
#pragma unroll
        for (int p = 0; p < 8; ++p) {
            int idx = p * 512 + tid;
            int row = idx >> 6;
            int colc = (idx & 63) * 4;
            f32x4 val = *(const f32x4*)&cls[row * 260 + colc];
            __builtin_nontemporal_store(val,
                (f32x4*)&outf[(size_t)(m0 + h * 64 + row) * N + n0 + colc]);
        }
    }
}

// ---------------------------------------------------------------------------
// flash attention, swapped-QK^T softmax, 32 q-rows per wave (two 16-row
// groups A/B sharing every K/V load), KVBLK=128, no online max, cvt_pk
// packed P.  Output staged through LDS -> wide 128B stores.
// ---------------------------------------------------------------------------
__global__ __launch_bounds__(256) void k_attn(const ushort_t* __restrict__ q,
        const ushort_t* __restrict__ k, const ushort_t* __restrict__ vT,
        ushort_t* __restrict__ yc) {
    __shared__ __align__(16) ushort_t P[4][32 * 136];
    const int lane = threadIdx.x & 63, wave = threadIdx.x >> 6;
    const int lr = lane & 15, lg = lane >> 4;
    const int bh = blockIdx.x;
    const int bb = bh / H_, hh = bh % H_;
    const int qrow0 = (gridDim.y - 1 - blockIdx.y) * 128 + wave * 32;
    const ushort_t* qb = q + (size_t)bh * T_ * D_;
    const ushort_t* kb = k + (size_t)bh * T_ * D_;
    const ushort_t* vb = vT + (size_t)bh * D_ * T_;

    bf16x8 aq0A = *(const bf16x8*)&qb[(qrow0 + lr) * D_ + lg * 8];
    bf16x8 aq1A = *(const bf16x8*)&qb[(qrow0 + lr) * D_ + 32 + lg * 8];
    bf16x8 aq0B = *(const bf16x8*)&qb[(qrow0 + 16 + lr) * D_ + lg * 8];
    bf16x8 aq1B = *(const bf16x8*)&qb[(qrow0 + 16 + lr) * D_ + 32 + lg * 8];

    f32x4 accA[4], accB[4];
    float lsA = 0.f, lsB = 0.f;
#pragma unroll
    for (int d = 0; d < 4; ++d) {
        accA[d] = (f32x4){0.f, 0.f, 0.f, 0.f};
        accB[d] = (f32x4){0.f, 0.f, 0.f, 0.f};
    }

    ushort_t* pw = &P[wave][0];
    const int kv_end = qrow0 + 32;
    for (int kv0 = 0; kv0 < kv_end; kv0 += 128) {
        const bool fullA = (kv0 + 127 <= qrow0);          // wave-uniform
        const bool fullB = (kv0 + 127 <= qrow0 + 16);
        uint2 wA[8], wB[8];
        float psA = 0.f, psB = 0.f;
#pragma unroll
        for (int j = 0; j < 8; ++j) {
            bf16x8 bk0 = *(const bf16x8*)&kb[(kv0 + j * 16 + lr) * D_ + lg * 8];
            bf16x8 bk1 = *(const bf16x8*)&kb[(kv0 + j * 16 + lr) * D_ + 32 + lg * 8];
            f32x4 sA = (f32x4){0.f, 0.f, 0.f, 0.f};
            f32x4 sB = (f32x4){0.f, 0.f, 0.f, 0.f};
            __builtin_amdgcn_s_setprio(1);
            sA = __builtin_amdgcn_mfma_f32_16x16x32_bf16(bk0, aq0A, sA, 0, 0, 0);
            sA = __builtin_amdgcn_mfma_f32_16x16x32_bf16(bk1, aq1A, sA, 0, 0, 0);
            sB = __builtin_amdgcn_mfma_f32_16x16x32_bf16(bk0, aq0B, sB, 0, 0, 0);
            sB = __builtin_amdgcn_mfma_f32_16x16x32_bf16(bk1, aq1B, sB, 0, 0, 0);
            __builtin_amdgcn_s_setprio(0);
            // lane holds S^T[k = kv0+j*16+lg*4+r][q = qrow0+(16)+lr]
            float pA[4], pB[4];
            const int kcb = kv0 + j * 16 + lg * 4;
            if (fullA) {
#pragma unroll
                for (int r = 0; r < 4; ++r) { pA[r] = __expf(sA[r] * 0.125f); psA += pA[r]; }
            } else {
#pragma unroll
                for (int r = 0; r < 4; ++r) {
                    pA[r] = (kcb + r <= qrow0 + lr) ? __expf(sA[r] * 0.125f) : 0.f;
                    psA += pA[r];
                }
            }
            if (fullB) {
#pragma unroll
                for (int r = 0; r < 4; ++r) { pB[r] = __expf(sB[r] * 0.125f); psB += pB[r]; }
            } else {
#pragma unroll
                for (int r = 0; r < 4; ++r) {
                    pB[r] = (kcb + r <= qrow0 + 16 + lr) ? __expf(sB[r] * 0.125f) : 0.f;
                    psB += pB[r];
                }
            }
            unsigned int w0, w1;
            asm("v_cvt_pk_bf16_f32 %0, %1, %2" : "=v"(w0) : "v"(pA[0]), "v"(pA[1]));
            asm("v_cvt_pk_bf16_f32 %0, %1, %2" : "=v"(w1) : "v"(pA[2]), "v"(pA[3]));
            wA[j].x = w0; wA[j].y = w1;
            asm("v_cvt_pk_bf16_f32 %0, %1, %2" : "=v"(w0) : "v"(pB[0]), "v"(pB[1]));
            asm("v_cvt_pk_bf16_f32 %0, %1, %2" : "=v"(w1) : "v"(pB[2]), "v"(pB[3]));
            wB[j].x = w0; wB[j].y = w1;
        }
        psA += __shfl_xor(psA, 16);
        psA += __shfl_xor(psA, 32);
        lsA += psA;
        psB += __shfl_xor(psB, 16);
        psB += __shfl_xor(psB, 32);
        lsB += psB;

        // previous iteration's pa reads must be complete before overwrite
        asm volatile("s_waitcnt lgkmcnt(0)" ::: "memory");
        __builtin_amdgcn_sched_barrier(0);
#pragma unroll
        for (int j = 0; j < 8; ++j) {
            *(uint2*)&pw[lr * 136 + j * 16 + lg * 4]        = wA[j];
            *(uint2*)&pw[(16 + lr) * 136 + j * 16 + lg * 4] = wB[j];
        }
        asm volatile("s_waitcnt lgkmcnt(0)" ::: "memory");
        __builtin_amdgcn_sched_barrier(0);
        bf16x8 paA[4], paB[4];
#pragma unroll
        for (int ks = 0; ks < 4; ++ks) {
            paA[ks] = *(const bf16x8*)&pw[lr * 136 + ks * 32 + lg * 8];
            paB[ks] = *(const bf16x8*)&pw[(16 + lr) * 136 + ks * 32 + lg * 8];
        }
#pragma unroll
        for (int d = 0; d < 4; ++d) {
            __builtin_amdgcn_s_setprio(1);
#pragma unroll
            for (int ks = 0; ks < 4; ++ks) {
                bf16x8 bv = *(const bf16x8*)&vb[(d * 16 + lr) * T_ + kv0 + ks * 32 + lg * 8];
                accA[d] = __builtin_amdgcn_mfma_f32_16x16x32_bf16(paA[ks], bv, accA[d], 0, 0, 0);
                accB[d] = __builtin_amdgcn_mfma_f32_16x16x32_bf16(paB[ks], bv, accB[d], 0, 0, 0);
            }
            __builtin_amdgcn_s_setprio(0);
        }
    }
    float invA[4], invB[4];
#pragma unroll
    for (int r = 0; r < 4; ++r) {
        invA[r] = 1.0f / __shfl(lsA, lg * 4 + r);
        invB[r] = 1.0f / __shfl(lsB, lg * 4 + r);
    }

    // stage output tile (32 x 64) in LDS, then wide 128B stores along d
    asm volatile("s_waitcnt lgkmcnt(0)" ::: "memory");
    __builtin_amdgcn_sched_barrier(0);
#pragma unroll
    for (int d = 0; d < 4; ++d)
#pragma unroll
        for (int r = 0; r < 4; ++r) {
            pw[(lg * 4 + r) * 72 + d * 16 + lr]        = f2b(accA[d][r] * invA[r]);
            pw[(16 + lg * 4 + r) * 72 + d * 16 + lr]   = f2b(accB[d][r] * invB[r]);
        }
    asm volatile("s_waitcnt lgkmcnt(0)" ::: "memory");
    __builtin_amdgcn_sched_barrier(0);
#pragma unroll
    for (int p = 0; p < 4; ++p) {
        int row = p * 8 + (lane >> 3);
        int colc = (lane & 7) * 8;
        u16x8 val = *(const u16x8*)&pw[row * 72 + colc];
        *(u16x8*)&yc[((size_t)bb * T_ + qrow0 + row) * C_ + hh * D_ + colc] = val;
    }
}

// ---------------------------------------------------------------------------
extern "C" void kernel_launch(void* const* d_in, const int* in_sizes, int n_in,
                              void* d_out, int out_size, void* d_ws, size_t ws_size,
                              hipStream_t stream) {
    (void)in_sizes; (void)n_in; (void)out_size; (void)ws_size;
    const int*   idx  = (const int*)d_in[0];
    const float* tok  = (const float*)d_in[1];
    const float* pos  = (const float*)d_in[2];
    const float* Wq   = (const float*)d_in[3];
    const float* Wk   = (const float*)d_in[4];
    const float* Wv   = (const float*)d_in[5];
    const float* Wp   = (const float*)d_in[6];
    const float* bp   = (const float*)d_in[7];
    const float* ln1s = (const float*)d_in[8];
    const float* ln1b = (const float*)d_in[9];
    const float* ln2s = (const float*)d_in[10];
    const float* ln2b = (const float*)d_in[11];
    const float* W1   = (const float*)d_in[12];
    const float* b1   = (const float*)d_in[13];
    const float* W2   = (const float*)d_in[14];
    const float* b2   = (const float*)d_in[15];
    const float* lnfs = (const float*)d_in[16];
    const float* lnfb = (const float*)d_in[17];
    const float* Wh   = (const float*)d_in[18];
    float* out = (float*)d_out;

    char* ws = (char*)d_ws;
    size_t off = 0;
    auto alloc = [&](size_t bytes) { void* p = ws + off; off += (bytes + 255) & ~(size_t)255; return p; };

    const size_t CCE = (size_t)C_ * C_;
    const size_t CFE = (size_t)C_ * F_;
    ushort_t* wCC  = (ushort_t*)alloc(16 * CCE * 2);
    ushort_t* w1T  = (ushort_t*)alloc((size_t)L_ * CFE * 2);
    ushort_t* w2T  = (ushort_t*)alloc((size_t)L_ * CFE * 2);
    ushort_t* whT  = (ushort_t*)alloc((size_t)C_ * V_ * 2);
    ushort_t* x    = (ushort_t*)alloc((size_t)B_ * T_ * C_ * 2);   // bf16 residual stream
    ushort_t* h    = (ushort_t*)alloc((size_t)B_ * T_ * C_ * 2);
    ushort_t* qb_  = (ushort_t*)alloc((size_t)B_ * T_ * C_ * 2);
    ushort_t* kb_  = (ushort_t*)alloc((size_t)B_ * T_ * C_ * 2);
    ushort_t* vTb  = (ushort_t*)alloc((size_t)B_ * T_ * C_ * 2);
    ushort_t* yc   = (ushort_t*)alloc((size_t)B_ * T_ * C_ * 2);
    ushort_t* mh   = (ushort_t*)alloc((size_t)B_ * T_ * F_ * 2);

    dim3 tb(32, 8);
    k_tcvt16<<<dim3(24, 24, 16), tb, 0, stream>>>(Wq, Wk, Wv, Wp, wCC);
    k_tcvt<<<dim3(96, 24, 4), tb, 0, stream>>>(W1, w1T, C_, F_);
    k_tcvt<<<dim3(24, 96, 4), tb, 0, stream>>>(W2, w2T, F_, C_);
    k_tcvt<<<dim3(1000, 24, 1), tb, 0, stream>>>(Wh, whT, C_, V_);

    k_embed<<<3072, 256, 0, stream>>>(idx, tok, pos, x);

    for (int l = 0; l < L_; ++l) {
        k_ln<<<1024, 256, 0, stream>>>(x, ln1s + l * C_, ln1b + l * C_, h);
        k_gemm<3><<<18 * 32, 256, 0, stream>>>(h, wCC + (size_t)(l * 4) * CCE,
            nullptr, nullptr, nullptr, qb_, kb_, vTb, 4096, 3 * C_, C_);
        k_attn<<<dim3(48, 8), 256, 0, stream>>>(qb_, kb_, vTb, yc);
        k_gemm<2><<<6 * 32, 256, 0, stream>>>(yc, wCC + (size_t)(l * 4 + 3) * CCE,
            bp + l * C_, nullptr, nullptr, x, x, nullptr, 4096, C_, C_);
        k_ln<<<1024, 256, 0, stream>>>(x, ln2s + l * C_, ln2b + l * C_, h);
        k_gemm<1><<<24 * 32, 256, 0, stream>>>(h, w1T + (size_t)l * CFE,
            b1 + l * F_, nullptr, nullptr, mh, nullptr, nullptr, 4096, F_, C_);
        k_gemm<2><<<6 * 32, 256, 0, stream>>>(mh, w2T + (size_t)l * CFE,
            b2 + l * C_, nullptr, nullptr, x, x, nullptr, 4096, C_, F_);
    }
    k_ln<<<1024, 256, 0, stream>>>(x, lnfs, lnfb, h);
    k_gemmh<<<4000, 512, 0, stream>>>(h, whT, out, 4096, V_, C_);
}